// Round 1
// baseline (258.613 us; speedup 1.0000x reference)
//
#include <hip/hip_runtime.h>
#include <math.h>

// Problem constants (fixed by the reference)
#define NNODES 20000
#define NEDGES 320000
#define FIN    512
#define HIDD   128
#define OUTD   128
#define NH     4
#define NC     64
#define HC     256   // NH*NC

// ---------------------------------------------------------------------------
// Generic fp32 GEMM: C[M,N] = A[M,K] @ B[K,N] (+bias) (+relu)
// Tile: 64 (M) x 128 (N), BK=32, 256 threads, 4x8 outputs/thread.
// A staged transposed in LDS (padded stride 68 -> conflict-light), B row-major.
// Requires: N % 128 == 0, K % 32 == 0. M tail guarded.
// ---------------------------------------------------------------------------
__global__ __launch_bounds__(256)
void sgemm_kernel(const float* __restrict__ A, const float* __restrict__ B,
                  const float* __restrict__ bias, float* __restrict__ C,
                  int M, int N, int K, int do_relu) {
    __shared__ float  As[32][68];       // [k][row], padded
    __shared__ float4 Bs[32][32];       // [k][col4]  (128 cols)

    const int tid = threadIdx.x;
    const int tx = tid & 15;            // 0..15 -> col groups
    const int ty = tid >> 4;            // 0..15 -> row group (4 rows)
    const int m0 = blockIdx.x * 64;
    const int n0 = blockIdx.y * 128;

    const int K4 = K >> 2;
    const int N4 = N >> 2;
    const float4* A4 = (const float4*)A;
    const float4* B4 = (const float4*)B;

    float acc[4][8];
    #pragma unroll
    for (int i = 0; i < 4; ++i)
        #pragma unroll
        for (int j = 0; j < 8; ++j) acc[i][j] = 0.f;

    const int ksteps = K >> 5;
    for (int kt = 0; kt < ksteps; ++kt) {
        const int k0 = kt << 5;
        // --- load A tile (64 x 32), store transposed As[k][r]
        #pragma unroll
        for (int i = 0; i < 2; ++i) {
            int f  = i * 256 + tid;     // 0..511
            int r  = f >> 3;            // 0..63
            int c4 = f & 7;             // 0..7
            float4 v = make_float4(0.f, 0.f, 0.f, 0.f);
            if (m0 + r < M) v = A4[(size_t)(m0 + r) * K4 + (k0 >> 2) + c4];
            int kk = c4 << 2;
            As[kk + 0][r] = v.x;
            As[kk + 1][r] = v.y;
            As[kk + 2][r] = v.z;
            As[kk + 3][r] = v.w;
        }
        // --- load B tile (32 x 128)
        #pragma unroll
        for (int i = 0; i < 4; ++i) {
            int f   = i * 256 + tid;    // 0..1023
            int row = f >> 5;           // 0..31
            int c4  = f & 31;           // 0..31
            Bs[row][c4] = B4[(size_t)(k0 + row) * N4 + (n0 >> 2) + c4];
        }
        __syncthreads();

        #pragma unroll
        for (int k = 0; k < 32; ++k) {
            const float4 av = *reinterpret_cast<const float4*>(&As[k][ty << 2]);
            const float4 b0 = Bs[k][tx];
            const float4 b1 = Bs[k][tx + 16];
            const float a[4] = {av.x, av.y, av.z, av.w};
            #pragma unroll
            for (int i = 0; i < 4; ++i) {
                acc[i][0] += a[i] * b0.x;
                acc[i][1] += a[i] * b0.y;
                acc[i][2] += a[i] * b0.z;
                acc[i][3] += a[i] * b0.w;
                acc[i][4] += a[i] * b1.x;
                acc[i][5] += a[i] * b1.y;
                acc[i][6] += a[i] * b1.z;
                acc[i][7] += a[i] * b1.w;
            }
        }
        __syncthreads();
    }

    // epilogue
    float4 bv0 = make_float4(0.f, 0.f, 0.f, 0.f), bv1 = bv0;
    if (bias) {
        bv0 = ((const float4*)bias)[(n0 >> 2) + tx];
        bv1 = ((const float4*)bias)[(n0 >> 2) + tx + 16];
    }
    float4* C4 = (float4*)C;
    #pragma unroll
    for (int i = 0; i < 4; ++i) {
        int row = m0 + (ty << 2) + i;
        if (row >= M) continue;
        float4 r0 = make_float4(acc[i][0] + bv0.x, acc[i][1] + bv0.y,
                                acc[i][2] + bv0.z, acc[i][3] + bv0.w);
        float4 r1 = make_float4(acc[i][4] + bv1.x, acc[i][5] + bv1.y,
                                acc[i][6] + bv1.z, acc[i][7] + bv1.w);
        if (do_relu) {
            r0.x = fmaxf(r0.x, 0.f); r0.y = fmaxf(r0.y, 0.f);
            r0.z = fmaxf(r0.z, 0.f); r0.w = fmaxf(r0.w, 0.f);
            r1.x = fmaxf(r1.x, 0.f); r1.y = fmaxf(r1.y, 0.f);
            r1.z = fmaxf(r1.z, 0.f); r1.w = fmaxf(r1.w, 0.f);
        }
        C4[(size_t)row * N4 + (n0 >> 2) + tx]      = r0;
        C4[(size_t)row * N4 + (n0 >> 2) + tx + 16] = r1;
    }
}

// ---------------------------------------------------------------------------
// a_src[n,h] = dot(xg[n, h*64 : h*64+64], att_src[h]);  same for a_dst
// one thread per (n,h)
// ---------------------------------------------------------------------------
__global__ __launch_bounds__(256)
void att_dots_kernel(const float* __restrict__ xg, const float* __restrict__ att_src,
                     const float* __restrict__ att_dst, float* __restrict__ a_src,
                     float* __restrict__ a_dst, int n) {
    int idx = blockIdx.x * 256 + threadIdx.x;
    if (idx >= n * NH) return;
    int node = idx >> 2;
    int h = idx & 3;
    const float4* xr = (const float4*)(xg + (size_t)node * HC + h * NC);
    const float4* s4 = (const float4*)(att_src + h * NC);
    const float4* d4 = (const float4*)(att_dst + h * NC);
    float ss = 0.f, dd = 0.f;
    #pragma unroll
    for (int j = 0; j < 16; ++j) {
        float4 v = xr[j], a = s4[j], b = d4[j];
        ss += v.x * a.x + v.y * a.y + v.z * a.z + v.w * a.w;
        dd += v.x * b.x + v.y * b.y + v.z * b.z + v.w * b.w;
    }
    a_src[idx] = ss;
    a_dst[idx] = dd;
}

// ---------------------------------------------------------------------------
// CSR build: deg init (1 for self-loop), count, scan, scatter
// ---------------------------------------------------------------------------
__global__ void init_deg_kernel(int* __restrict__ deg, int n) {
    int i = blockIdx.x * 256 + threadIdx.x;
    if (i < n) deg[i] = 1;  // self loop
}

__global__ void count_deg_kernel(const int* __restrict__ dst, int* __restrict__ deg, int e) {
    int i = blockIdx.x * 256 + threadIdx.x;
    if (i < e) atomicAdd(&deg[dst[i]], 1);
}

__global__ __launch_bounds__(1024)
void scan_offsets_kernel(const int* __restrict__ deg, int* __restrict__ offs,
                         int* __restrict__ cursor, int n) {
    __shared__ int buf[1024];
    __shared__ int carry_s;
    int tid = threadIdx.x;
    if (tid == 0) carry_s = 0;
    __syncthreads();
    int nch = (n + 1023) >> 10;
    for (int c = 0; c < nch; ++c) {
        int i = (c << 10) + tid;
        int v = (i < n) ? deg[i] : 0;
        buf[tid] = v;
        __syncthreads();
        for (int d = 1; d < 1024; d <<= 1) {
            int t = (tid >= d) ? buf[tid - d] : 0;
            __syncthreads();
            buf[tid] += t;
            __syncthreads();
        }
        int base = carry_s;
        int excl = base + buf[tid] - v;
        if (i < n) { offs[i] = excl; cursor[i] = excl; }
        __syncthreads();
        if (tid == 1023) carry_s = base + buf[1023];
        __syncthreads();
    }
    if (tid == 0) offs[n] = carry_s;
}

__global__ void scatter_kernel(const int* __restrict__ src, const int* __restrict__ dst,
                               int* __restrict__ cursor, int* __restrict__ csr_src,
                               int e, int n) {
    int i = blockIdx.x * 256 + threadIdx.x;
    if (i < e) {
        int s = src[i], d = dst[i];
        csr_src[atomicAdd(&cursor[d], 1)] = s;
    } else if (i < e + n) {
        int node = i - e;
        csr_src[atomicAdd(&cursor[node], 1)] = node;  // self loop
    }
}

// ---------------------------------------------------------------------------
// Aggregation: one wave (64 lanes) per destination node.
// lane l owns channels [4l, 4l+4) -> head h = l>>4.
// pass 1: per-head max of e = leakyrelu(a_src[s]+a_dst[i])
// pass 2: den = sum exp(e-m); acc += exp(e-m) * xg[s]
// out = acc/(den+1e-16) + bias
// ---------------------------------------------------------------------------
__global__ __launch_bounds__(256)
void gat_aggregate_kernel(const float* __restrict__ xg, const float* __restrict__ a_src,
                          const float* __restrict__ a_dst, const int* __restrict__ offs,
                          const int* __restrict__ csr_src, const float* __restrict__ bias,
                          float* __restrict__ out, int n) {
    int wave = threadIdx.x >> 6;
    int lane = threadIdx.x & 63;
    int node = blockIdx.x * 4 + wave;
    if (node >= n) return;
    int h = lane >> 4;
    int beg = offs[node], end = offs[node + 1];
    float adst = a_dst[node * NH + h];

    float mx = -INFINITY;
    for (int j = beg; j < end; ++j) {
        int s = csr_src[j];
        float e = a_src[s * NH + h] + adst;
        e = (e > 0.f) ? e : 0.2f * e;
        mx = fmaxf(mx, e);
    }

    const float4* xg4 = (const float4*)xg;
    float4 acc = make_float4(0.f, 0.f, 0.f, 0.f);
    float den = 0.f;
    for (int j = beg; j < end; ++j) {
        int s = csr_src[j];
        float e = a_src[s * NH + h] + adst;
        e = (e > 0.f) ? e : 0.2f * e;
        float ex = __expf(e - mx);
        den += ex;
        float4 v = xg4[(size_t)s * 64 + lane];
        acc.x += ex * v.x; acc.y += ex * v.y; acc.z += ex * v.z; acc.w += ex * v.w;
    }
    float inv = 1.f / (den + 1e-16f);
    float4 bv = ((const float4*)bias)[lane];
    float4 o = make_float4(acc.x * inv + bv.x, acc.y * inv + bv.y,
                           acc.z * inv + bv.z, acc.w * inv + bv.w);
    ((float4*)out)[(size_t)node * 64 + lane] = o;
}

// ---------------------------------------------------------------------------
extern "C" void kernel_launch(void* const* d_in, const int* in_sizes, int n_in,
                              void* d_out, int out_size, void* d_ws, size_t ws_size,
                              hipStream_t stream) {
    const float* x       = (const float*)d_in[0];
    const int*   ei      = (const int*)d_in[1];
    const float* W1      = (const float*)d_in[2];
    const float* b1      = (const float*)d_in[3];
    const float* W2      = (const float*)d_in[4];
    const float* b2      = (const float*)d_in[5];
    const float* Wg      = (const float*)d_in[6];
    const float* att_src = (const float*)d_in[7];
    const float* att_dst = (const float*)d_in[8];
    const float* bias_g  = (const float*)d_in[9];

    const int Nn = in_sizes[0] / FIN;       // 20000
    const int E  = in_sizes[1] / 2;         // 320000
    const int* e_src = ei;
    const int* e_dst = ei + E;

    // workspace layout (all 256B aligned)
    char* w = (char*)d_ws;
    auto alloc = [&](size_t bytes) { char* p = w; w += (bytes + 255) & ~(size_t)255; return p; };
    float* h1   = (float*)alloc((size_t)Nn * HIDD * 4);
    float* hh   = (float*)alloc((size_t)Nn * OUTD * 4);
    float* xg   = (float*)alloc((size_t)Nn * HC * 4);
    float* asrc = (float*)alloc((size_t)Nn * NH * 4);
    float* adst = (float*)alloc((size_t)Nn * NH * 4);
    int* deg    = (int*)alloc((size_t)Nn * 4);
    int* offs   = (int*)alloc((size_t)(Nn + 1) * 4);
    int* cursor = (int*)alloc((size_t)Nn * 4);
    int* csr    = (int*)alloc((size_t)(E + Nn) * 4);

    dim3 blk(256);
    int gm = (Nn + 63) / 64;

    // MLP encoder
    sgemm_kernel<<<dim3(gm, 1), blk, 0, stream>>>(x,  W1, b1, h1, Nn, HIDD, FIN,  1);
    sgemm_kernel<<<dim3(gm, 1), blk, 0, stream>>>(h1, W2, b2, hh, Nn, OUTD, HIDD, 0);
    // GAT projection (bias added at the very end)
    sgemm_kernel<<<dim3(gm, 2), blk, 0, stream>>>(hh, Wg, nullptr, xg, Nn, HC, OUTD, 0);

    // attention dots
    att_dots_kernel<<<dim3((Nn * NH + 255) / 256), blk, 0, stream>>>(
        xg, att_src, att_dst, asrc, adst, Nn);

    // CSR build (by destination), self-loops included
    init_deg_kernel<<<dim3((Nn + 255) / 256), blk, 0, stream>>>(deg, Nn);
    count_deg_kernel<<<dim3((E + 255) / 256), blk, 0, stream>>>(e_dst, deg, E);
    scan_offsets_kernel<<<dim3(1), dim3(1024), 0, stream>>>(deg, offs, cursor, Nn);
    scatter_kernel<<<dim3((E + Nn + 255) / 256), blk, 0, stream>>>(
        e_src, e_dst, cursor, csr, E, Nn);

    // softmax + aggregation, one wave per node
    gat_aggregate_kernel<<<dim3((Nn + 3) / 4), blk, 0, stream>>>(
        xg, asrc, adst, offs, csr, bias_g, (float*)d_out, Nn);
}

// Round 2
// 189.741 us; speedup vs baseline: 1.3630x; 1.3630x over previous
//
#include <hip/hip_runtime.h>
#include <math.h>

// Problem constants (fixed by the reference)
#define NNODES 20000
#define NEDGES 320000
#define FIN    512
#define HIDD   128
#define OUTD   128
#define NH     4
#define NC     64
#define HC     256   // NH*NC

typedef short bf16x8 __attribute__((ext_vector_type(8)));
typedef float f32x4  __attribute__((ext_vector_type(4)));

__device__ __forceinline__ unsigned short f2bf(float f) {
    unsigned int u = __float_as_uint(f);
    unsigned int r = 0x7fffu + ((u >> 16) & 1u);
    return (unsigned short)((u + r) >> 16);
}

// ---------------------------------------------------------------------------
// Weight prep: W1t[n][k] = bf16(W1[k][n])   (K=512, N=128)
// ---------------------------------------------------------------------------
__global__ __launch_bounds__(256)
void transpose_cast_kernel(const float* __restrict__ W, unsigned short* __restrict__ Wt,
                           int K, int N) {
    int idx = blockIdx.x * 256 + threadIdx.x;
    if (idx >= K * N) return;
    int n = idx / K, k = idx % K;           // write coalesced in k
    Wt[idx] = f2bf(W[(size_t)k * N + n]);
}

// ---------------------------------------------------------------------------
// Fuse W2@Wg -> W2gt (bf16, [256][128]) and b2g[n] = sum_j b2[j]*Wg[j][n]
// ---------------------------------------------------------------------------
__global__ __launch_bounds__(256)
void fuse_w2g_kernel(const float* __restrict__ W2, const float* __restrict__ b2,
                     const float* __restrict__ Wg, unsigned short* __restrict__ W2gt,
                     float* __restrict__ b2g) {
    int idx = blockIdx.x * 256 + threadIdx.x;   // 256*128
    if (idx >= HC * HIDD) return;
    int n = idx >> 7;        // 0..255 output col
    int k = idx & 127;       // 0..127 input row
    float s = 0.f;
    #pragma unroll 8
    for (int t = 0; t < HIDD; ++t)
        s += W2[(size_t)k * OUTD + t] * Wg[(size_t)t * HC + n];
    W2gt[(size_t)n * HIDD + k] = f2bf(s);
    if (k == 0) {
        float t2 = 0.f;
        #pragma unroll 8
        for (int t = 0; t < OUTD; ++t) t2 += b2[t] * Wg[(size_t)t * HC + n];
        b2g[n] = t2;
    }
}

// ---------------------------------------------------------------------------
// bf16 MFMA GEMM: C[M,N] = A[M,K] @ Bt^T (+bias)(+relu)
//   Bt: [N][K] bf16 (pre-transposed weights)
//   A:  fp32 [M][K] (converted during staging) or bf16 [M][K]
//   C:  fp32 or bf16
// Tiles: BM=64, BN=128, BK=64; 4 waves (2x2), wave tile 32x64 (2x4 16x16 frags)
// LDS XOR-swizzled (byte ^= (row&7)<<4) -> conflict-free ds_read_b128.
// Requires N%128==0, K%64==0.
// ---------------------------------------------------------------------------
template<bool A_IS_F32, bool OUT_BF16>
__global__ __launch_bounds__(256)
void mfma_gemm_kernel(const void* __restrict__ Aptr,
                      const unsigned short* __restrict__ Bt,
                      const float* __restrict__ bias,
                      void* __restrict__ Cptr,
                      int M, int N, int K, int do_relu) {
    __shared__ unsigned short As[64 * 64];    // 8 KB  (row stride 128 B)
    __shared__ unsigned short Bs[128 * 64];   // 16 KB (col-major: [n][k])

    const int tid  = threadIdx.x;
    const int lane = tid & 63;
    const int w    = tid >> 6;
    const int wr   = w >> 1;          // 0..1
    const int wc   = w & 1;           // 0..1
    const int m0   = blockIdx.x * 64;
    const int n0   = blockIdx.y * 128;

    char* pA = (char*)As;
    char* pB = (char*)Bs;

    f32x4 acc[2][4];
    #pragma unroll
    for (int m = 0; m < 2; ++m)
        #pragma unroll
        for (int n = 0; n < 4; ++n) acc[m][n] = (f32x4){0.f, 0.f, 0.f, 0.f};

    for (int k0 = 0; k0 < K; k0 += 64) {
        // ---- stage A tile (64 rows x 64 k) ----
        if (A_IS_F32) {
            const int row = tid >> 2;
            const int ks  = (tid & 3) << 4;          // 0,16,32,48
            const bool ok = (m0 + row) < M;
            const float4* Ap = (const float4*)((const float*)Aptr +
                               (size_t)(m0 + row) * K + k0 + ks);
            float4 f0 = make_float4(0,0,0,0), f1 = f0, f2 = f0, f3 = f0;
            if (ok) { f0 = Ap[0]; f1 = Ap[1]; f2 = Ap[2]; f3 = Ap[3]; }
            unsigned short u[16];
            u[0]=f2bf(f0.x); u[1]=f2bf(f0.y); u[2]=f2bf(f0.z); u[3]=f2bf(f0.w);
            u[4]=f2bf(f1.x); u[5]=f2bf(f1.y); u[6]=f2bf(f1.z); u[7]=f2bf(f1.w);
            u[8]=f2bf(f2.x); u[9]=f2bf(f2.y); u[10]=f2bf(f2.z); u[11]=f2bf(f2.w);
            u[12]=f2bf(f3.x); u[13]=f2bf(f3.y); u[14]=f2bf(f3.z); u[15]=f2bf(f3.w);
            const int sw = (row & 7) << 4;
            const int base = row * 128 + ks * 2;
            *(bf16x8*)(pA + ((base     ) ^ sw)) = *(bf16x8*)&u[0];
            *(bf16x8*)(pA + ((base + 16) ^ sw)) = *(bf16x8*)&u[8];
        } else {
            const unsigned short* Ab = (const unsigned short*)Aptr;
            #pragma unroll
            for (int i = 0; i < 2; ++i) {
                int s   = tid + i * 256;       // 0..511
                int row = s >> 3;              // 0..63
                int sg  = s & 7;               // 16B segment
                bf16x8 v = {};
                if ((m0 + row) < M)
                    v = *(const bf16x8*)(Ab + (size_t)(m0 + row) * K + k0 + sg * 8);
                *(bf16x8*)(pA + (((row * 128 + sg * 16)) ^ ((row & 7) << 4))) = v;
            }
        }
        // ---- stage B tile (128 cols x 64 k), already [n][k] ----
        #pragma unroll
        for (int i = 0; i < 4; ++i) {
            int s   = tid + i * 256;           // 0..1023
            int col = s >> 3;                  // 0..127
            int sg  = s & 7;
            bf16x8 v = *(const bf16x8*)(Bt + (size_t)(n0 + col) * K + k0 + sg * 8);
            *(bf16x8*)(pB + (((col * 128 + sg * 16)) ^ ((col & 7) << 4))) = v;
        }
        __syncthreads();

        // ---- compute: 2 k-subtiles of 32 ----
        #pragma unroll
        for (int ks = 0; ks < 2; ++ks) {
            const int kb = ks * 64 + ((lane >> 4) << 4);   // byte offset of k-frag
            bf16x8 a[2], b[4];
            #pragma unroll
            for (int m = 0; m < 2; ++m) {
                int row = wr * 32 + m * 16 + (lane & 15);
                a[m] = *(const bf16x8*)(pA + ((row * 128 + kb) ^ ((row & 7) << 4)));
            }
            #pragma unroll
            for (int n = 0; n < 4; ++n) {
                int col = wc * 64 + n * 16 + (lane & 15);
                b[n] = *(const bf16x8*)(pB + ((col * 128 + kb) ^ ((col & 7) << 4)));
            }
            #pragma unroll
            for (int m = 0; m < 2; ++m)
                #pragma unroll
                for (int n = 0; n < 4; ++n)
                    acc[m][n] = __builtin_amdgcn_mfma_f32_16x16x32_bf16(
                        a[m], b[n], acc[m][n], 0, 0, 0);
        }
        __syncthreads();
    }

    // ---- epilogue ----
    #pragma unroll
    for (int n = 0; n < 4; ++n) {
        const int col = n0 + wc * 64 + n * 16 + (lane & 15);
        const float bv = bias ? bias[col] : 0.f;
        #pragma unroll
        for (int m = 0; m < 2; ++m) {
            #pragma unroll
            for (int r = 0; r < 4; ++r) {
                const int row = m0 + wr * 32 + m * 16 + ((lane >> 4) << 2) + r;
                if (row >= M) continue;
                float v = acc[m][n][r] + bv;
                if (do_relu) v = fmaxf(v, 0.f);
                if (OUT_BF16)
                    ((unsigned short*)Cptr)[(size_t)row * N + col] = f2bf(v);
                else
                    ((float*)Cptr)[(size_t)row * N + col] = v;
            }
        }
    }
}

// ---------------------------------------------------------------------------
// a_src[n,h] = dot(xg[n, h*64:(h+1)*64], att_src[h]);  same for a_dst
// ---------------------------------------------------------------------------
__global__ __launch_bounds__(256)
void att_dots_kernel(const float* __restrict__ xg, const float* __restrict__ att_src,
                     const float* __restrict__ att_dst, float* __restrict__ a_src,
                     float* __restrict__ a_dst, int n) {
    int idx = blockIdx.x * 256 + threadIdx.x;
    if (idx >= n * NH) return;
    int node = idx >> 2;
    int h = idx & 3;
    const float4* xr = (const float4*)(xg + (size_t)node * HC + h * NC);
    const float4* s4 = (const float4*)(att_src + h * NC);
    const float4* d4 = (const float4*)(att_dst + h * NC);
    float ss = 0.f, dd = 0.f;
    #pragma unroll
    for (int j = 0; j < 16; ++j) {
        float4 v = xr[j], a = s4[j], b = d4[j];
        ss += v.x * a.x + v.y * a.y + v.z * a.z + v.w * a.w;
        dd += v.x * b.x + v.y * b.y + v.z * b.z + v.w * b.w;
    }
    a_src[idx] = ss;
    a_dst[idx] = dd;
}

// ---------------------------------------------------------------------------
// CSR build
// ---------------------------------------------------------------------------
__global__ void init_deg_kernel(int* __restrict__ deg, int n) {
    int i = blockIdx.x * 256 + threadIdx.x;
    if (i < n) deg[i] = 1;  // self loop
}

__global__ void count_deg_kernel(const int* __restrict__ dst, int* __restrict__ deg, int e) {
    int i = blockIdx.x * 256 + threadIdx.x;
    if (i < e) atomicAdd(&deg[dst[i]], 1);
}

__global__ __launch_bounds__(1024)
void scan_offsets_kernel(const int* __restrict__ deg, int* __restrict__ offs,
                         int* __restrict__ cursor, int n) {
    __shared__ int wsum[16];
    __shared__ int wbase[16];
    __shared__ int carry_s;
    const int tid = threadIdx.x, lane = tid & 63, w = tid >> 6;
    if (tid == 0) carry_s = 0;
    __syncthreads();
    const int nch = (n + 1023) >> 10;
    for (int c = 0; c < nch; ++c) {
        int i = (c << 10) + tid;
        int v = (i < n) ? deg[i] : 0;
        int s = v;
        #pragma unroll
        for (int d = 1; d < 64; d <<= 1) {
            int t = __shfl_up(s, d);
            if (lane >= d) s += t;
        }
        if (lane == 63) wsum[w] = s;
        __syncthreads();
        if (tid == 0) {
            int run = carry_s;
            #pragma unroll
            for (int j = 0; j < 16; ++j) { int t = wsum[j]; wbase[j] = run; run += t; }
            carry_s = run;
        }
        __syncthreads();
        int excl = wbase[w] + s - v;
        if (i < n) { offs[i] = excl; cursor[i] = excl; }
        __syncthreads();
    }
    if (tid == 0) offs[n] = carry_s;
}

__global__ void scatter_kernel(const int* __restrict__ src, const int* __restrict__ dst,
                               int* __restrict__ cursor, int* __restrict__ csr_src,
                               int e, int n) {
    int i = blockIdx.x * 256 + threadIdx.x;
    if (i < e) {
        int s = src[i], d = dst[i];
        csr_src[atomicAdd(&cursor[d], 1)] = s;
    } else if (i < e + n) {
        int node = i - e;
        csr_src[atomicAdd(&cursor[node], 1)] = node;  // self loop
    }
}

// ---------------------------------------------------------------------------
// Aggregation: one wave per destination node (see round-1 notes)
// ---------------------------------------------------------------------------
__global__ __launch_bounds__(256)
void gat_aggregate_kernel(const float* __restrict__ xg, const float* __restrict__ a_src,
                          const float* __restrict__ a_dst, const int* __restrict__ offs,
                          const int* __restrict__ csr_src, const float* __restrict__ bias,
                          float* __restrict__ out, int n) {
    int wave = threadIdx.x >> 6;
    int lane = threadIdx.x & 63;
    int node = blockIdx.x * 4 + wave;
    if (node >= n) return;
    int h = lane >> 4;
    int beg = offs[node], end = offs[node + 1];
    float adst = a_dst[node * NH + h];

    float mx = -INFINITY;
    for (int j = beg; j < end; ++j) {
        int s = csr_src[j];
        float e = a_src[s * NH + h] + adst;
        e = (e > 0.f) ? e : 0.2f * e;
        mx = fmaxf(mx, e);
    }

    const float4* xg4 = (const float4*)xg;
    float4 acc = make_float4(0.f, 0.f, 0.f, 0.f);
    float den = 0.f;
    for (int j = beg; j < end; ++j) {
        int s = csr_src[j];
        float e = a_src[s * NH + h] + adst;
        e = (e > 0.f) ? e : 0.2f * e;
        float ex = __expf(e - mx);
        den += ex;
        float4 v = xg4[(size_t)s * 64 + lane];
        acc.x += ex * v.x; acc.y += ex * v.y; acc.z += ex * v.z; acc.w += ex * v.w;
    }
    float inv = 1.f / (den + 1e-16f);
    float4 bv = ((const float4*)bias)[lane];
    float4 o = make_float4(acc.x * inv + bv.x, acc.y * inv + bv.y,
                           acc.z * inv + bv.z, acc.w * inv + bv.w);
    ((float4*)out)[(size_t)node * 64 + lane] = o;
}

// ---------------------------------------------------------------------------
extern "C" void kernel_launch(void* const* d_in, const int* in_sizes, int n_in,
                              void* d_out, int out_size, void* d_ws, size_t ws_size,
                              hipStream_t stream) {
    const float* x       = (const float*)d_in[0];
    const int*   ei      = (const int*)d_in[1];
    const float* W1      = (const float*)d_in[2];
    const float* b1      = (const float*)d_in[3];
    const float* W2      = (const float*)d_in[4];
    const float* b2      = (const float*)d_in[5];
    const float* Wg      = (const float*)d_in[6];
    const float* att_src = (const float*)d_in[7];
    const float* att_dst = (const float*)d_in[8];
    const float* bias_g  = (const float*)d_in[9];

    const int Nn = in_sizes[0] / FIN;       // 20000
    const int E  = in_sizes[1] / 2;         // 320000
    const int* e_src = ei;
    const int* e_dst = ei + E;

    char* w = (char*)d_ws;
    auto alloc = [&](size_t bytes) { char* p = w; w += (bytes + 255) & ~(size_t)255; return p; };
    unsigned short* W1t  = (unsigned short*)alloc((size_t)OUTD * FIN * 2);   // [128][512]
    unsigned short* W2gt = (unsigned short*)alloc((size_t)HC * HIDD * 2);    // [256][128]
    float* b2g  = (float*)alloc(HC * 4);
    unsigned short* h1 = (unsigned short*)alloc((size_t)Nn * HIDD * 2);      // bf16
    float* xg   = (float*)alloc((size_t)Nn * HC * 4);
    float* asrc = (float*)alloc((size_t)Nn * NH * 4);
    float* adst = (float*)alloc((size_t)Nn * NH * 4);
    int* deg    = (int*)alloc((size_t)Nn * 4);
    int* offs   = (int*)alloc((size_t)(Nn + 1) * 4);
    int* cursor = (int*)alloc((size_t)Nn * 4);
    int* csr    = (int*)alloc((size_t)(E + Nn) * 4);

    dim3 blk(256);
    const int gm = (Nn + 63) / 64;

    // weight prep
    transpose_cast_kernel<<<dim3((FIN * HIDD + 255) / 256), blk, 0, stream>>>(W1, W1t, FIN, HIDD);
    fuse_w2g_kernel<<<dim3((HC * HIDD + 255) / 256), blk, 0, stream>>>(W2, b2, Wg, W2gt, b2g);

    // h1 = relu(x@W1 + b1)  [bf16 out]
    mfma_gemm_kernel<true, true><<<dim3(gm, 1), blk, 0, stream>>>(
        x, W1t, b1, h1, Nn, HIDD, FIN, 1);
    // xg = h1 @ W2g + b2g   [fp32 out]
    mfma_gemm_kernel<false, false><<<dim3(gm, 2), blk, 0, stream>>>(
        h1, W2gt, b2g, xg, Nn, HC, HIDD, 0);

    // attention dots
    att_dots_kernel<<<dim3((Nn * NH + 255) / 256), blk, 0, stream>>>(
        xg, att_src, att_dst, asrc, adst, Nn);

    // CSR build (by destination), self-loops included
    init_deg_kernel<<<dim3((Nn + 255) / 256), blk, 0, stream>>>(deg, Nn);
    count_deg_kernel<<<dim3((E + 255) / 256), blk, 0, stream>>>(e_dst, deg, E);
    scan_offsets_kernel<<<dim3(1), dim3(1024), 0, stream>>>(deg, offs, cursor, Nn);
    scatter_kernel<<<dim3((E + Nn + 255) / 256), blk, 0, stream>>>(
        e_src, e_dst, cursor, csr, E, Nn);

    // softmax + aggregation
    gat_aggregate_kernel<<<dim3((Nn + 3) / 4), blk, 0, stream>>>(
        xg, asrc, adst, offs, csr, bias_g, (float*)d_out, Nn);
}

// Round 3
// 153.689 us; speedup vs baseline: 1.6827x; 1.2346x over previous
//
#include <hip/hip_runtime.h>
#include <math.h>

// Problem constants (fixed by the reference)
#define NNODES 20000
#define NEDGES 320000
#define FIN    512
#define HIDD   128
#define OUTD   128
#define NH     4
#define NC     64
#define HC     256   // NH*NC

typedef short bf16x8 __attribute__((ext_vector_type(8)));
typedef float f32x4  __attribute__((ext_vector_type(4)));

__device__ __forceinline__ unsigned short f2bf(float f) {
    unsigned int u = __float_as_uint(f);
    unsigned int r = 0x7fffu + ((u >> 16) & 1u);
    return (unsigned short)((u + r) >> 16);
}
__device__ __forceinline__ float b2f(short t) {
    return __uint_as_float(((unsigned)(unsigned short)t) << 16);
}
__device__ __forceinline__ float4 f4max(float4 a, float4 b) {
    return make_float4(fmaxf(a.x,b.x), fmaxf(a.y,b.y), fmaxf(a.z,b.z), fmaxf(a.w,b.w));
}
__device__ __forceinline__ float4 f4add(float4 a, float4 b) {
    return make_float4(a.x+b.x, a.y+b.y, a.z+b.z, a.w+b.w);
}
__device__ __forceinline__ float4 f4sub(float4 a, float4 b) {
    return make_float4(a.x-b.x, a.y-b.y, a.z-b.z, a.w-b.w);
}
__device__ __forceinline__ float4 f4mul(float4 a, float4 b) {
    return make_float4(a.x*b.x, a.y*b.y, a.z*b.z, a.w*b.w);
}
__device__ __forceinline__ float4 f4exp(float4 a) {
    return make_float4(__expf(a.x), __expf(a.y), __expf(a.z), __expf(a.w));
}
__device__ __forceinline__ float4 shflx4(float4 v, int m) {
    return make_float4(__shfl_xor(v.x,m), __shfl_xor(v.y,m), __shfl_xor(v.z,m), __shfl_xor(v.w,m));
}

// ---------------------------------------------------------------------------
// Weight prep: W1t[n][k] = bf16(W1[k][n])
// ---------------------------------------------------------------------------
__global__ __launch_bounds__(256)
void transpose_cast_kernel(const float* __restrict__ W, unsigned short* __restrict__ Wt,
                           int K, int N) {
    int idx = blockIdx.x * 256 + threadIdx.x;
    if (idx >= K * N) return;
    int n = idx / K, k = idx % K;
    Wt[idx] = f2bf(W[(size_t)k * N + n]);
}

// ---------------------------------------------------------------------------
// Fuse W2@Wg -> W2gt (bf16, [256][128]) and b2g[n] = sum_j b2[j]*Wg[j][n]
// ---------------------------------------------------------------------------
__global__ __launch_bounds__(256)
void fuse_w2g_kernel(const float* __restrict__ W2, const float* __restrict__ b2,
                     const float* __restrict__ Wg, unsigned short* __restrict__ W2gt,
                     float* __restrict__ b2g) {
    int idx = blockIdx.x * 256 + threadIdx.x;
    if (idx >= HC * HIDD) return;
    int n = idx >> 7;
    int k = idx & 127;
    float s = 0.f;
    #pragma unroll 8
    for (int t = 0; t < HIDD; ++t)
        s += W2[(size_t)k * OUTD + t] * Wg[(size_t)t * HC + n];
    W2gt[(size_t)n * HIDD + k] = f2bf(s);
    if (k == 0) {
        float t2 = 0.f;
        #pragma unroll 8
        for (int t = 0; t < OUTD; ++t) t2 += b2[t] * Wg[(size_t)t * HC + n];
        b2g[n] = t2;
    }
}

// ---------------------------------------------------------------------------
// bf16 MFMA GEMM (unchanged from round 2): C[M,N] = A[M,K] @ Bt^T (+bias)(+relu)
// ---------------------------------------------------------------------------
template<bool A_IS_F32, bool OUT_BF16>
__global__ __launch_bounds__(256)
void mfma_gemm_kernel(const void* __restrict__ Aptr,
                      const unsigned short* __restrict__ Bt,
                      const float* __restrict__ bias,
                      void* __restrict__ Cptr,
                      int M, int N, int K, int do_relu) {
    __shared__ unsigned short As[64 * 64];
    __shared__ unsigned short Bs[128 * 64];

    const int tid  = threadIdx.x;
    const int lane = tid & 63;
    const int w    = tid >> 6;
    const int wr   = w >> 1;
    const int wc   = w & 1;
    const int m0   = blockIdx.x * 64;
    const int n0   = blockIdx.y * 128;

    char* pA = (char*)As;
    char* pB = (char*)Bs;

    f32x4 acc[2][4];
    #pragma unroll
    for (int m = 0; m < 2; ++m)
        #pragma unroll
        for (int n = 0; n < 4; ++n) acc[m][n] = (f32x4){0.f, 0.f, 0.f, 0.f};

    for (int k0 = 0; k0 < K; k0 += 64) {
        if (A_IS_F32) {
            const int row = tid >> 2;
            const int ks  = (tid & 3) << 4;
            const bool ok = (m0 + row) < M;
            const float4* Ap = (const float4*)((const float*)Aptr +
                               (size_t)(m0 + row) * K + k0 + ks);
            float4 f0 = make_float4(0,0,0,0), f1 = f0, f2 = f0, f3 = f0;
            if (ok) { f0 = Ap[0]; f1 = Ap[1]; f2 = Ap[2]; f3 = Ap[3]; }
            unsigned short u[16];
            u[0]=f2bf(f0.x); u[1]=f2bf(f0.y); u[2]=f2bf(f0.z); u[3]=f2bf(f0.w);
            u[4]=f2bf(f1.x); u[5]=f2bf(f1.y); u[6]=f2bf(f1.z); u[7]=f2bf(f1.w);
            u[8]=f2bf(f2.x); u[9]=f2bf(f2.y); u[10]=f2bf(f2.z); u[11]=f2bf(f2.w);
            u[12]=f2bf(f3.x); u[13]=f2bf(f3.y); u[14]=f2bf(f3.z); u[15]=f2bf(f3.w);
            const int sw = (row & 7) << 4;
            const int base = row * 128 + ks * 2;
            *(bf16x8*)(pA + ((base     ) ^ sw)) = *(bf16x8*)&u[0];
            *(bf16x8*)(pA + ((base + 16) ^ sw)) = *(bf16x8*)&u[8];
        } else {
            const unsigned short* Ab = (const unsigned short*)Aptr;
            #pragma unroll
            for (int i = 0; i < 2; ++i) {
                int s   = tid + i * 256;
                int row = s >> 3;
                int sg  = s & 7;
                bf16x8 v = {};
                if ((m0 + row) < M)
                    v = *(const bf16x8*)(Ab + (size_t)(m0 + row) * K + k0 + sg * 8);
                *(bf16x8*)(pA + (((row * 128 + sg * 16)) ^ ((row & 7) << 4))) = v;
            }
        }
        #pragma unroll
        for (int i = 0; i < 4; ++i) {
            int s   = tid + i * 256;
            int col = s >> 3;
            int sg  = s & 7;
            bf16x8 v = *(const bf16x8*)(Bt + (size_t)(n0 + col) * K + k0 + sg * 8);
            *(bf16x8*)(pB + (((col * 128 + sg * 16)) ^ ((col & 7) << 4))) = v;
        }
        __syncthreads();

        #pragma unroll
        for (int ks = 0; ks < 2; ++ks) {
            const int kb = ks * 64 + ((lane >> 4) << 4);
            bf16x8 a[2], b[4];
            #pragma unroll
            for (int m = 0; m < 2; ++m) {
                int row = wr * 32 + m * 16 + (lane & 15);
                a[m] = *(const bf16x8*)(pA + ((row * 128 + kb) ^ ((row & 7) << 4)));
            }
            #pragma unroll
            for (int n = 0; n < 4; ++n) {
                int col = wc * 64 + n * 16 + (lane & 15);
                b[n] = *(const bf16x8*)(pB + ((col * 128 + kb) ^ ((col & 7) << 4)));
            }
            #pragma unroll
            for (int m = 0; m < 2; ++m)
                #pragma unroll
                for (int n = 0; n < 4; ++n)
                    acc[m][n] = __builtin_amdgcn_mfma_f32_16x16x32_bf16(
                        a[m], b[n], acc[m][n], 0, 0, 0);
        }
        __syncthreads();
    }

    #pragma unroll
    for (int n = 0; n < 4; ++n) {
        const int col = n0 + wc * 64 + n * 16 + (lane & 15);
        const float bv = bias ? bias[col] : 0.f;
        #pragma unroll
        for (int m = 0; m < 2; ++m) {
            #pragma unroll
            for (int r = 0; r < 4; ++r) {
                const int row = m0 + wr * 32 + m * 16 + ((lane >> 4) << 2) + r;
                if (row >= M) continue;
                float v = acc[m][n][r] + bv;
                if (do_relu) v = fmaxf(v, 0.f);
                if (OUT_BF16)
                    ((unsigned short*)Cptr)[(size_t)row * N + col] = f2bf(v);
                else
                    ((float*)Cptr)[(size_t)row * N + col] = v;
            }
        }
    }
}

// ---------------------------------------------------------------------------
// a_src[n,h], a_dst[n,h] from bf16 xg
// ---------------------------------------------------------------------------
__global__ __launch_bounds__(256)
void att_dots_kernel(const unsigned short* __restrict__ xgb, const float* __restrict__ att_src,
                     const float* __restrict__ att_dst, float* __restrict__ a_src,
                     float* __restrict__ a_dst, int n) {
    int idx = blockIdx.x * 256 + threadIdx.x;
    if (idx >= n * NH) return;
    int node = idx >> 2;
    int h = idx & 3;
    const bf16x8* xr = (const bf16x8*)(xgb + (size_t)node * HC + h * NC);
    const float* sa = att_src + h * NC;
    const float* da = att_dst + h * NC;
    float ss = 0.f, dd = 0.f;
    #pragma unroll
    for (int j = 0; j < 8; ++j) {
        bf16x8 v = xr[j];
        #pragma unroll
        for (int t = 0; t < 8; ++t) {
            float f = b2f(v[t]);
            ss += f * sa[j * 8 + t];
            dd += f * da[j * 8 + t];
        }
    }
    a_src[idx] = ss;
    a_dst[idx] = dd;
}

// ---------------------------------------------------------------------------
// CSR build
// ---------------------------------------------------------------------------
__global__ void init_deg_kernel(int* __restrict__ deg, int n) {
    int i = blockIdx.x * 256 + threadIdx.x;
    if (i < n) deg[i] = 1;  // self loop
}

__global__ void count_deg_kernel(const int* __restrict__ dst, int* __restrict__ deg, int e) {
    int i = blockIdx.x * 256 + threadIdx.x;
    if (i < e) atomicAdd(&deg[dst[i]], 1);
}

// Single-block scan, 20 elements/thread in registers, 2 barriers total.
// Requires n <= 20480.
__global__ __launch_bounds__(1024)
void scan_offsets_kernel(const int* __restrict__ deg, int* __restrict__ offs,
                         int* __restrict__ cursor, int n) {
    __shared__ int wsum[16], wbase[16];
    const int tid = threadIdx.x, lane = tid & 63, w = tid >> 6;
    const int i0 = tid * 20;
    int loc[20];
    int s = 0;
    #pragma unroll
    for (int k = 0; k < 20; ++k) {
        int i = i0 + k;
        int v = (i < n) ? deg[i] : 0;
        loc[k] = s;
        s += v;
    }
    int incl = s;
    #pragma unroll
    for (int d = 1; d < 64; d <<= 1) {
        int t = __shfl_up(incl, d);
        if (lane >= d) incl += t;
    }
    if (lane == 63) wsum[w] = incl;
    __syncthreads();
    if (w == 0) {
        int v = (lane < 16) ? wsum[lane] : 0;
        int sc = v;
        #pragma unroll
        for (int d = 1; d < 16; d <<= 1) {
            int t = __shfl_up(sc, d);
            if (lane >= d) sc += t;
        }
        if (lane < 16) wbase[lane] = sc - v;
    }
    __syncthreads();
    const int excl = wbase[w] + incl - s;
    #pragma unroll
    for (int k = 0; k < 20; ++k) {
        int i = i0 + k;
        if (i < n) { int o = excl + loc[k]; offs[i] = o; cursor[i] = o; }
    }
    if (tid == 1023) offs[n] = excl + s;
}

// Scatter edges into CSR slots AND compute per-edge logits e = leakyrelu(a_src[s]+a_dst[d])
__global__ void scatter_e_kernel(const int* __restrict__ src, const int* __restrict__ dst,
                                 const float4* __restrict__ asrc, const float4* __restrict__ adst,
                                 int* __restrict__ cursor, int* __restrict__ csr_src,
                                 float4* __restrict__ e_csr, int e, int n) {
    int i = blockIdx.x * 256 + threadIdx.x;
    int s, d;
    if (i < e)          { s = src[i]; d = dst[i]; }
    else if (i < e + n) { s = i - e;  d = i - e;  }
    else return;
    float4 a = asrc[s], b = adst[d];
    float4 ev = make_float4(a.x + b.x, a.y + b.y, a.z + b.z, a.w + b.w);
    ev.x = ev.x > 0.f ? ev.x : 0.2f * ev.x;
    ev.y = ev.y > 0.f ? ev.y : 0.2f * ev.y;
    ev.z = ev.z > 0.f ? ev.z : 0.2f * ev.z;
    ev.w = ev.w > 0.f ? ev.w : 0.2f * ev.w;
    int slot = atomicAdd(&cursor[d], 1);
    csr_src[slot] = s;
    e_csr[slot] = ev;
}

// ---------------------------------------------------------------------------
// Aggregation v2: one wave per node.
// Pass A: lane-parallel online softmax over chunks of 64 edges (coalesced e_csr
//         reads, shfl-reduce per head). Stores ex/src of the chunk in LDS.
// Pass B: lanes split 32/32 over channel halves; each inner step processes 2
//         edges with 16B/lane bf16 gathers, 4-edge unroll for MLP.
// ---------------------------------------------------------------------------
__global__ __launch_bounds__(256)
void gat_aggregate2_kernel(const unsigned short* __restrict__ xgb,
                           const float4* __restrict__ e_csr,
                           const int* __restrict__ offs, const int* __restrict__ csr_src,
                           const float* __restrict__ bias, float* __restrict__ out, int n) {
    __shared__ float4 exbuf[4][64];
    __shared__ int    sbuf[4][64];
    const int wv   = threadIdx.x >> 6;
    const int lane = threadIdx.x & 63;
    const int node = blockIdx.x * 4 + wv;
    if (node >= n) return;
    const int beg = offs[node], end = offs[node + 1];
    const int deg = end - beg;

    // ---- pass A: online max & denominator, lane-parallel ----
    float4 m   = make_float4(-INFINITY, -INFINITY, -INFINITY, -INFINITY);
    float4 den = make_float4(0.f, 0.f, 0.f, 0.f);
    for (int c0 = 0; c0 < deg; c0 += 64) {
        int idx = beg + c0 + lane;
        bool ok = idx < end;
        float4 e = ok ? e_csr[idx]
                      : make_float4(-INFINITY, -INFINITY, -INFINITY, -INFINITY);
        int s = ok ? csr_src[idx] : 0;
        float4 cm = e;
        #pragma unroll
        for (int dd = 32; dd >= 1; dd >>= 1) cm = f4max(cm, shflx4(cm, dd));
        float4 nm = f4max(m, cm);
        float4 ex = f4exp(f4sub(e, nm));        // masked lanes: exp(-inf)=0
        exbuf[wv][lane] = ex;                   // valid for the LAST chunk
        sbuf[wv][lane]  = s;
        float4 cs = ex;
        #pragma unroll
        for (int dd = 32; dd >= 1; dd >>= 1) cs = f4add(cs, shflx4(cs, dd));
        den = f4add(f4mul(den, f4exp(f4sub(m, nm))), cs);
        m = nm;
    }

    const int hi = lane >> 5;        // which half-wave
    const int ll = lane & 31;        // lane within half: owns channels 8*ll..8*ll+7
    const int h  = ll >> 3;          // head of those channels
    const float denh = (h == 0) ? den.x : (h == 1) ? den.y : (h == 2) ? den.z : den.w;
    const float inv = 1.f / (denh + 1e-16f);

    float4 acc0 = make_float4(0.f, 0.f, 0.f, 0.f);
    float4 acc1 = make_float4(0.f, 0.f, 0.f, 0.f);
    const float* exf = (const float*)&exbuf[wv][0];

    auto run_chunk = [&](int cn) {
        int j = 0;
        for (; j + 4 <= cn; j += 4) {
            int jA = j + hi, jB = j + 2 + hi;
            int sA = sbuf[wv][jA], sB = sbuf[wv][jB];
            float wA = exf[jA * 4 + h], wB = exf[jB * 4 + h];
            bf16x8 vA = *(const bf16x8*)(xgb + (size_t)sA * HC + ll * 8);
            bf16x8 vB = *(const bf16x8*)(xgb + (size_t)sB * HC + ll * 8);
            acc0.x += wA * b2f(vA[0]); acc0.y += wA * b2f(vA[1]);
            acc0.z += wA * b2f(vA[2]); acc0.w += wA * b2f(vA[3]);
            acc1.x += wA * b2f(vA[4]); acc1.y += wA * b2f(vA[5]);
            acc1.z += wA * b2f(vA[6]); acc1.w += wA * b2f(vA[7]);
            acc0.x += wB * b2f(vB[0]); acc0.y += wB * b2f(vB[1]);
            acc0.z += wB * b2f(vB[2]); acc0.w += wB * b2f(vB[3]);
            acc1.x += wB * b2f(vB[4]); acc1.y += wB * b2f(vB[5]);
            acc1.z += wB * b2f(vB[6]); acc1.w += wB * b2f(vB[7]);
        }
        for (; j < cn; j += 2) {
            int jj = j + hi;
            bool ok2 = jj < cn;
            int s = sbuf[wv][ok2 ? jj : 0];
            float wgt = ok2 ? exf[jj * 4 + h] : 0.f;
            bf16x8 v = *(const bf16x8*)(xgb + (size_t)s * HC + ll * 8);
            acc0.x += wgt * b2f(v[0]); acc0.y += wgt * b2f(v[1]);
            acc0.z += wgt * b2f(v[2]); acc0.w += wgt * b2f(v[3]);
            acc1.x += wgt * b2f(v[4]); acc1.y += wgt * b2f(v[5]);
            acc1.z += wgt * b2f(v[6]); acc1.w += wgt * b2f(v[7]);
        }
    };

    if (deg <= 64) {
        run_chunk(deg);   // exbuf/sbuf already hold the (only) chunk with final m
    } else {
        for (int c0 = 0; c0 < deg; c0 += 64) {
            int idx = beg + c0 + lane;
            if (idx < end) {
                float4 e = e_csr[idx];
                exbuf[wv][lane] = f4exp(f4sub(e, m));
                sbuf[wv][lane]  = csr_src[idx];
            }
            int cn = deg - c0; if (cn > 64) cn = 64;
            run_chunk(cn);
        }
    }

    // combine the two half-wave partial sums
    acc0.x += __shfl_xor(acc0.x, 32); acc0.y += __shfl_xor(acc0.y, 32);
    acc0.z += __shfl_xor(acc0.z, 32); acc0.w += __shfl_xor(acc0.w, 32);
    acc1.x += __shfl_xor(acc1.x, 32); acc1.y += __shfl_xor(acc1.y, 32);
    acc1.z += __shfl_xor(acc1.z, 32); acc1.w += __shfl_xor(acc1.w, 32);

    if (hi == 0) {
        const float4* b4 = (const float4*)bias;
        float4 bv0 = b4[ll * 2], bv1 = b4[ll * 2 + 1];
        float4 o0 = make_float4(acc0.x * inv + bv0.x, acc0.y * inv + bv0.y,
                                acc0.z * inv + bv0.z, acc0.w * inv + bv0.w);
        float4 o1 = make_float4(acc1.x * inv + bv1.x, acc1.y * inv + bv1.y,
                                acc1.z * inv + bv1.z, acc1.w * inv + bv1.w);
        float4* op = (float4*)(out + (size_t)node * HC) + ll * 2;
        op[0] = o0;
        op[1] = o1;
    }
}

// ---------------------------------------------------------------------------
extern "C" void kernel_launch(void* const* d_in, const int* in_sizes, int n_in,
                              void* d_out, int out_size, void* d_ws, size_t ws_size,
                              hipStream_t stream) {
    const float* x       = (const float*)d_in[0];
    const int*   ei      = (const int*)d_in[1];
    const float* W1      = (const float*)d_in[2];
    const float* b1      = (const float*)d_in[3];
    const float* W2      = (const float*)d_in[4];
    const float* b2      = (const float*)d_in[5];
    const float* Wg      = (const float*)d_in[6];
    const float* att_src = (const float*)d_in[7];
    const float* att_dst = (const float*)d_in[8];
    const float* bias_g  = (const float*)d_in[9];

    const int Nn = in_sizes[0] / FIN;       // 20000
    const int E  = in_sizes[1] / 2;         // 320000
    const int* e_src = ei;
    const int* e_dst = ei + E;

    char* w = (char*)d_ws;
    auto alloc = [&](size_t bytes) { char* p = w; w += (bytes + 255) & ~(size_t)255; return p; };
    unsigned short* W1t  = (unsigned short*)alloc((size_t)OUTD * FIN * 2);
    unsigned short* W2gt = (unsigned short*)alloc((size_t)HC * HIDD * 2);
    float* b2g  = (float*)alloc(HC * 4);
    unsigned short* h1  = (unsigned short*)alloc((size_t)Nn * HIDD * 2);
    unsigned short* xgb = (unsigned short*)alloc((size_t)Nn * HC * 2);
    float* asrc = (float*)alloc((size_t)Nn * NH * 4);
    float* adst = (float*)alloc((size_t)Nn * NH * 4);
    int* deg    = (int*)alloc((size_t)Nn * 4);
    int* offs   = (int*)alloc((size_t)(Nn + 1) * 4);
    int* cursor = (int*)alloc((size_t)Nn * 4);
    int* csr    = (int*)alloc((size_t)(E + Nn) * 4);
    float4* ecsr = (float4*)alloc((size_t)(E + Nn) * 16);

    dim3 blk(256);
    const int gm = (Nn + 63) / 64;

    // weight prep
    transpose_cast_kernel<<<dim3((FIN * HIDD + 255) / 256), blk, 0, stream>>>(W1, W1t, FIN, HIDD);
    fuse_w2g_kernel<<<dim3((HC * HIDD + 255) / 256), blk, 0, stream>>>(W2, b2, Wg, W2gt, b2g);

    // h1 = relu(x@W1 + b1)  [bf16]
    mfma_gemm_kernel<true, true><<<dim3(gm, 1), blk, 0, stream>>>(
        x, W1t, b1, h1, Nn, HIDD, FIN, 1);
    // xg = h1 @ W2g + b2g   [bf16]
    mfma_gemm_kernel<false, true><<<dim3(gm, 2), blk, 0, stream>>>(
        h1, W2gt, b2g, xgb, Nn, HC, HIDD, 0);

    // attention dots (fp32 out)
    att_dots_kernel<<<dim3((Nn * NH + 255) / 256), blk, 0, stream>>>(
        xgb, att_src, att_dst, asrc, adst, Nn);

    // CSR build + per-edge logits
    init_deg_kernel<<<dim3((Nn + 255) / 256), blk, 0, stream>>>(deg, Nn);
    count_deg_kernel<<<dim3((E + 255) / 256), blk, 0, stream>>>(e_dst, deg, E);
    scan_offsets_kernel<<<dim3(1), dim3(1024), 0, stream>>>(deg, offs, cursor, Nn);
    scatter_e_kernel<<<dim3((E + Nn + 255) / 256), blk, 0, stream>>>(
        e_src, e_dst, (const float4*)asrc, (const float4*)adst, cursor, csr, ecsr, E, Nn);

    // softmax + aggregation
    gat_aggregate2_kernel<<<dim3((Nn + 3) / 4), blk, 0, stream>>>(
        xgb, ecsr, offs, csr, bias_g, (float*)d_out, Nn);
}

// Round 4
// 130.125 us; speedup vs baseline: 1.9874x; 1.1811x over previous
//
#include <hip/hip_runtime.h>
#include <math.h>

// Problem constants (fixed by the reference)
#define NNODES 20000
#define NEDGES 320000
#define FIN    512
#define HIDD   128
#define OUTD   128
#define NH     4
#define NC     64
#define HC     256   // NH*NC

typedef short bf16x8 __attribute__((ext_vector_type(8)));
typedef float f32x4  __attribute__((ext_vector_type(4)));

__device__ __forceinline__ unsigned short f2bf(float f) {
    unsigned int u = __float_as_uint(f);
    unsigned int r = 0x7fffu + ((u >> 16) & 1u);
    return (unsigned short)((u + r) >> 16);
}
__device__ __forceinline__ float b2f(short t) {
    return __uint_as_float(((unsigned)(unsigned short)t) << 16);
}
__device__ __forceinline__ float4 f4max(float4 a, float4 b) {
    return make_float4(fmaxf(a.x,b.x), fmaxf(a.y,b.y), fmaxf(a.z,b.z), fmaxf(a.w,b.w));
}
__device__ __forceinline__ float4 f4add(float4 a, float4 b) {
    return make_float4(a.x+b.x, a.y+b.y, a.z+b.z, a.w+b.w);
}
__device__ __forceinline__ float4 f4sub(float4 a, float4 b) {
    return make_float4(a.x-b.x, a.y-b.y, a.z-b.z, a.w-b.w);
}
__device__ __forceinline__ float4 f4mul(float4 a, float4 b) {
    return make_float4(a.x*b.x, a.y*b.y, a.z*b.z, a.w*b.w);
}
__device__ __forceinline__ float4 f4exp(float4 a) {
    return make_float4(__expf(a.x), __expf(a.y), __expf(a.z), __expf(a.w));
}
__device__ __forceinline__ float4 shflx4(float4 v, int m) {
    return make_float4(__shfl_xor(v.x,m), __shfl_xor(v.y,m), __shfl_xor(v.z,m), __shfl_xor(v.w,m));
}

// ---------------------------------------------------------------------------
// Prep (fused): W1t transpose-cast | W2@Wg fuse + b2g | deg init
// ---------------------------------------------------------------------------
__global__ __launch_bounds__(256)
void prep_kernel(const float* __restrict__ W1, unsigned short* __restrict__ W1t,
                 const float* __restrict__ W2, const float* __restrict__ b2,
                 const float* __restrict__ Wg, unsigned short* __restrict__ W2gt,
                 float* __restrict__ b2g, int* __restrict__ deg, int n) {
    const int T1 = FIN * HIDD;      // 65536
    const int T2 = HC * HIDD;       // 32768
    int idx = blockIdx.x * 256 + threadIdx.x;
    if (idx < T1) {
        // W1t[n][k] = bf16(W1[k][n]),  idx = n*FIN + k
        int nn = idx / FIN, k = idx % FIN;
        W1t[idx] = f2bf(W1[(size_t)k * HIDD + nn]);
    } else if (idx < T1 + T2) {
        int local = idx - T1;
        int nn = local >> 7;         // 0..255 output col
        int k  = local & 127;        // 0..127 input row
        float s = 0.f;
        #pragma unroll 8
        for (int t = 0; t < HIDD; ++t)
            s += W2[(size_t)k * OUTD + t] * Wg[(size_t)t * HC + nn];
        W2gt[(size_t)nn * HIDD + k] = f2bf(s);
        if (k == 0) {
            float t2 = 0.f;
            #pragma unroll 8
            for (int t = 0; t < OUTD; ++t) t2 += b2[t] * Wg[(size_t)t * HC + nn];
            b2g[nn] = t2;
        }
    } else if (idx < T1 + T2 + n) {
        deg[idx - T1 - T2] = 1;     // self loop
    }
}

// ---------------------------------------------------------------------------
// bf16 MFMA GEMM: C[M,N] = A[M,K] @ Bt^T (+bias)(+relu)
//   Bt: [N][K] bf16 (pre-transposed weights); A fp32 (cast in staging) or bf16
// Tiles: BM x 128, BK=64; 4 waves (2x2); XOR-swizzled LDS.
// BM = 32 (625 blocks for M=20000; latency-friendly) or 64.
// ---------------------------------------------------------------------------
template<bool A_IS_F32, bool OUT_BF16, int BM>
__global__ __launch_bounds__(256)
void mfma_gemm_kernel(const void* __restrict__ Aptr,
                      const unsigned short* __restrict__ Bt,
                      const float* __restrict__ bias,
                      void* __restrict__ Cptr,
                      int M, int N, int K, int do_relu) {
    constexpr int MF = BM / 32;               // m-fragments per wave
    __shared__ unsigned short As[BM * 64];
    __shared__ unsigned short Bs[128 * 64];

    const int tid  = threadIdx.x;
    const int lane = tid & 63;
    const int w    = tid >> 6;
    const int wr   = w >> 1;
    const int wc   = w & 1;
    const int m0   = blockIdx.x * BM;
    const int n0   = blockIdx.y * 128;

    char* pA = (char*)As;
    char* pB = (char*)Bs;

    f32x4 acc[MF][4];
    #pragma unroll
    for (int m = 0; m < MF; ++m)
        #pragma unroll
        for (int n = 0; n < 4; ++n) acc[m][n] = (f32x4){0.f, 0.f, 0.f, 0.f};

    for (int k0 = 0; k0 < K; k0 += 64) {
        if (A_IS_F32) {
            if constexpr (BM == 64) {
                const int row = tid >> 2;
                const int ks  = (tid & 3) << 4;
                const bool ok = (m0 + row) < M;
                const float4* Ap = (const float4*)((const float*)Aptr +
                                   (size_t)(m0 + row) * K + k0 + ks);
                float4 f0 = make_float4(0,0,0,0), f1 = f0, f2 = f0, f3 = f0;
                if (ok) { f0 = Ap[0]; f1 = Ap[1]; f2 = Ap[2]; f3 = Ap[3]; }
                unsigned short u[16];
                u[0]=f2bf(f0.x); u[1]=f2bf(f0.y); u[2]=f2bf(f0.z); u[3]=f2bf(f0.w);
                u[4]=f2bf(f1.x); u[5]=f2bf(f1.y); u[6]=f2bf(f1.z); u[7]=f2bf(f1.w);
                u[8]=f2bf(f2.x); u[9]=f2bf(f2.y); u[10]=f2bf(f2.z); u[11]=f2bf(f2.w);
                u[12]=f2bf(f3.x); u[13]=f2bf(f3.y); u[14]=f2bf(f3.z); u[15]=f2bf(f3.w);
                const int sw = (row & 7) << 4;
                const int base = row * 128 + ks * 2;
                *(bf16x8*)(pA + ((base     ) ^ sw)) = *(bf16x8*)&u[0];
                *(bf16x8*)(pA + ((base + 16) ^ sw)) = *(bf16x8*)&u[8];
            } else {
                const int row = tid >> 3;                // 0..31
                const int sg  = tid & 7;                 // 8-float segment
                const bool ok = (m0 + row) < M;
                const float4* Ap = (const float4*)((const float*)Aptr +
                                   (size_t)(m0 + row) * K + k0 + sg * 8);
                float4 f0 = make_float4(0,0,0,0), f1 = f0;
                if (ok) { f0 = Ap[0]; f1 = Ap[1]; }
                unsigned short u[8];
                u[0]=f2bf(f0.x); u[1]=f2bf(f0.y); u[2]=f2bf(f0.z); u[3]=f2bf(f0.w);
                u[4]=f2bf(f1.x); u[5]=f2bf(f1.y); u[6]=f2bf(f1.z); u[7]=f2bf(f1.w);
                *(bf16x8*)(pA + (((row * 128 + sg * 16)) ^ ((row & 7) << 4))) = *(bf16x8*)&u[0];
            }
        } else {
            const unsigned short* Ab = (const unsigned short*)Aptr;
            #pragma unroll
            for (int i = 0; i < BM / 32; ++i) {
                int s   = tid + i * 256;
                int row = s >> 3;
                int sg  = s & 7;
                bf16x8 v = {};
                if ((m0 + row) < M)
                    v = *(const bf16x8*)(Ab + (size_t)(m0 + row) * K + k0 + sg * 8);
                *(bf16x8*)(pA + (((row * 128 + sg * 16)) ^ ((row & 7) << 4))) = v;
            }
        }
        #pragma unroll
        for (int i = 0; i < 4; ++i) {
            int s   = tid + i * 256;
            int col = s >> 3;
            int sg  = s & 7;
            bf16x8 v = *(const bf16x8*)(Bt + (size_t)(n0 + col) * K + k0 + sg * 8);
            *(bf16x8*)(pB + (((col * 128 + sg * 16)) ^ ((col & 7) << 4))) = v;
        }
        __syncthreads();

        #pragma unroll
        for (int ks = 0; ks < 2; ++ks) {
            const int kb = ks * 64 + ((lane >> 4) << 4);
            bf16x8 a[MF], b[4];
            #pragma unroll
            for (int m = 0; m < MF; ++m) {
                int row = wr * (16 * MF) + m * 16 + (lane & 15);
                a[m] = *(const bf16x8*)(pA + ((row * 128 + kb) ^ ((row & 7) << 4)));
            }
            #pragma unroll
            for (int n = 0; n < 4; ++n) {
                int col = wc * 64 + n * 16 + (lane & 15);
                b[n] = *(const bf16x8*)(pB + ((col * 128 + kb) ^ ((col & 7) << 4)));
            }
            #pragma unroll
            for (int m = 0; m < MF; ++m)
                #pragma unroll
                for (int n = 0; n < 4; ++n)
                    acc[m][n] = __builtin_amdgcn_mfma_f32_16x16x32_bf16(
                        a[m], b[n], acc[m][n], 0, 0, 0);
        }
        __syncthreads();
    }

    #pragma unroll
    for (int n = 0; n < 4; ++n) {
        const int col = n0 + wc * 64 + n * 16 + (lane & 15);
        const float bv = bias ? bias[col] : 0.f;
        #pragma unroll
        for (int m = 0; m < MF; ++m) {
            #pragma unroll
            for (int r = 0; r < 4; ++r) {
                const int row = m0 + wr * (16 * MF) + m * 16 + ((lane >> 4) << 2) + r;
                if (row >= M) continue;
                float v = acc[m][n][r] + bv;
                if (do_relu) v = fmaxf(v, 0.f);
                if (OUT_BF16)
                    ((unsigned short*)Cptr)[(size_t)row * N + col] = f2bf(v);
                else
                    ((float*)Cptr)[(size_t)row * N + col] = v;
            }
        }
    }
}

// ---------------------------------------------------------------------------
// Fused: attention dots (first nb_dots blocks) | degree count (rest)
// ---------------------------------------------------------------------------
__global__ __launch_bounds__(256)
void dots_count_kernel(const unsigned short* __restrict__ xgb,
                       const float* __restrict__ att_src, const float* __restrict__ att_dst,
                       float* __restrict__ a_src, float* __restrict__ a_dst,
                       const int* __restrict__ dst, int* __restrict__ deg,
                       int n, int e, int nb_dots) {
    if ((int)blockIdx.x < nb_dots) {
        int idx = blockIdx.x * 256 + threadIdx.x;
        if (idx >= n * NH) return;
        int node = idx >> 2;
        int h = idx & 3;
        const bf16x8* xr = (const bf16x8*)(xgb + (size_t)node * HC + h * NC);
        const float* sa = att_src + h * NC;
        const float* da = att_dst + h * NC;
        float ss = 0.f, dd = 0.f;
        #pragma unroll
        for (int j = 0; j < 8; ++j) {
            bf16x8 v = xr[j];
            #pragma unroll
            for (int t = 0; t < 8; ++t) {
                float f = b2f(v[t]);
                ss += f * sa[j * 8 + t];
                dd += f * da[j * 8 + t];
            }
        }
        a_src[idx] = ss;
        a_dst[idx] = dd;
    } else {
        int i = (blockIdx.x - nb_dots) * 256 + threadIdx.x;
        if (i < e) atomicAdd(&deg[dst[i]], 1);
    }
}

// ---------------------------------------------------------------------------
// Single-block scan, 20 elems/thread in registers, 2 barriers. n <= 20480.
// ---------------------------------------------------------------------------
__global__ __launch_bounds__(1024)
void scan_offsets_kernel(const int* __restrict__ deg, int* __restrict__ offs,
                         int* __restrict__ cursor, int n) {
    __shared__ int wsum[16], wbase[16];
    const int tid = threadIdx.x, lane = tid & 63, w = tid >> 6;
    const int i0 = tid * 20;
    int loc[20];
    int s = 0;
    #pragma unroll
    for (int k = 0; k < 20; ++k) {
        int i = i0 + k;
        int v = (i < n) ? deg[i] : 0;
        loc[k] = s;
        s += v;
    }
    int incl = s;
    #pragma unroll
    for (int d = 1; d < 64; d <<= 1) {
        int t = __shfl_up(incl, d);
        if (lane >= d) incl += t;
    }
    if (lane == 63) wsum[w] = incl;
    __syncthreads();
    if (w == 0) {
        int v = (lane < 16) ? wsum[lane] : 0;
        int sc = v;
        #pragma unroll
        for (int d = 1; d < 16; d <<= 1) {
            int t = __shfl_up(sc, d);
            if (lane >= d) sc += t;
        }
        if (lane < 16) wbase[lane] = sc - v;
    }
    __syncthreads();
    const int excl = wbase[w] + incl - s;
    #pragma unroll
    for (int k = 0; k < 20; ++k) {
        int i = i0 + k;
        if (i < n) { int o = excl + loc[k]; offs[i] = o; cursor[i] = o; }
    }
    if (tid == 1023) offs[n] = excl + s;
}

// ---------------------------------------------------------------------------
// Scatter edges (and self-loops) into CSR slots
// ---------------------------------------------------------------------------
__global__ void scatter_kernel(const int* __restrict__ src, const int* __restrict__ dst,
                               int* __restrict__ cursor, int* __restrict__ csr_src,
                               int e, int n) {
    int i = blockIdx.x * 256 + threadIdx.x;
    if (i < e) {
        int s = src[i], d = dst[i];
        csr_src[atomicAdd(&cursor[d], 1)] = s;
    } else if (i < e + n) {
        int node = i - e;
        csr_src[atomicAdd(&cursor[node], 1)] = node;
    }
}

// ---------------------------------------------------------------------------
// Aggregation v3: one wave per node.
// Pass A: lane-parallel softmax; logits computed in-register from asrc gather
//         (L2-resident 320KB) + wave-uniform adst. exp/src cached in LDS.
// Pass B: half-wave channel split; 8-edge unroll (4 gathers in flight/half).
// ---------------------------------------------------------------------------
__global__ __launch_bounds__(256)
void gat_aggregate3_kernel(const unsigned short* __restrict__ xgb,
                           const float4* __restrict__ asrc4,
                           const float4* __restrict__ adst4,
                           const int* __restrict__ offs, const int* __restrict__ csr_src,
                           const float* __restrict__ bias, float* __restrict__ out, int n) {
    __shared__ float4 exbuf[4][64];
    __shared__ int    sbuf[4][64];
    const int wv   = threadIdx.x >> 6;
    const int lane = threadIdx.x & 63;
    const int node = blockIdx.x * 4 + wv;
    if (node >= n) return;
    const int beg = offs[node], end = offs[node + 1];
    const int deg = end - beg;
    const float4 adstv = adst4[node];

    // ---- pass A ----
    float4 m   = make_float4(-INFINITY, -INFINITY, -INFINITY, -INFINITY);
    float4 den = make_float4(0.f, 0.f, 0.f, 0.f);
    for (int c0 = 0; c0 < deg; c0 += 64) {
        int idx = beg + c0 + lane;
        bool ok = idx < end;
        int s = ok ? csr_src[idx] : 0;
        float4 e = make_float4(-INFINITY, -INFINITY, -INFINITY, -INFINITY);
        if (ok) {
            float4 a = asrc4[s];
            e = f4add(a, adstv);
            e.x = e.x > 0.f ? e.x : 0.2f * e.x;
            e.y = e.y > 0.f ? e.y : 0.2f * e.y;
            e.z = e.z > 0.f ? e.z : 0.2f * e.z;
            e.w = e.w > 0.f ? e.w : 0.2f * e.w;
        }
        float4 cm = e;
        #pragma unroll
        for (int dd = 32; dd >= 1; dd >>= 1) cm = f4max(cm, shflx4(cm, dd));
        float4 nm = f4max(m, cm);
        float4 ex = f4exp(f4sub(e, nm));      // masked lanes: exp(-inf)=0
        exbuf[wv][lane] = ex;
        sbuf[wv][lane]  = s;
        float4 cs = ex;
        #pragma unroll
        for (int dd = 32; dd >= 1; dd >>= 1) cs = f4add(cs, shflx4(cs, dd));
        den = f4add(f4mul(den, f4exp(f4sub(m, nm))), cs);
        m = nm;
    }

    const int hi = lane >> 5;
    const int ll = lane & 31;       // owns channels 8*ll .. 8*ll+7
    const int h  = ll >> 3;
    const float denh = (h == 0) ? den.x : (h == 1) ? den.y : (h == 2) ? den.z : den.w;
    const float inv = 1.f / (denh + 1e-16f);

    float4 acc0 = make_float4(0.f, 0.f, 0.f, 0.f);
    float4 acc1 = make_float4(0.f, 0.f, 0.f, 0.f);
    const float* exf = (const float*)&exbuf[wv][0];

    auto do_edge = [&](int jj) {
        int s = sbuf[wv][jj];
        float wgt = exf[jj * 4 + h];
        bf16x8 v = *(const bf16x8*)(xgb + (size_t)s * HC + ll * 8);
        acc0.x += wgt * b2f(v[0]); acc0.y += wgt * b2f(v[1]);
        acc0.z += wgt * b2f(v[2]); acc0.w += wgt * b2f(v[3]);
        acc1.x += wgt * b2f(v[4]); acc1.y += wgt * b2f(v[5]);
        acc1.z += wgt * b2f(v[6]); acc1.w += wgt * b2f(v[7]);
    };

    auto run_chunk = [&](int cn) {
        int j = 0;
        for (; j + 8 <= cn; j += 8) {
            int j0 = j + hi, j1 = j + 2 + hi, j2 = j + 4 + hi, j3 = j + 6 + hi;
            int s0 = sbuf[wv][j0], s1 = sbuf[wv][j1], s2 = sbuf[wv][j2], s3 = sbuf[wv][j3];
            float w0 = exf[j0*4+h], w1 = exf[j1*4+h], w2 = exf[j2*4+h], w3 = exf[j3*4+h];
            bf16x8 v0 = *(const bf16x8*)(xgb + (size_t)s0 * HC + ll * 8);
            bf16x8 v1 = *(const bf16x8*)(xgb + (size_t)s1 * HC + ll * 8);
            bf16x8 v2 = *(const bf16x8*)(xgb + (size_t)s2 * HC + ll * 8);
            bf16x8 v3 = *(const bf16x8*)(xgb + (size_t)s3 * HC + ll * 8);
            acc0.x += w0*b2f(v0[0]); acc0.y += w0*b2f(v0[1]); acc0.z += w0*b2f(v0[2]); acc0.w += w0*b2f(v0[3]);
            acc1.x += w0*b2f(v0[4]); acc1.y += w0*b2f(v0[5]); acc1.z += w0*b2f(v0[6]); acc1.w += w0*b2f(v0[7]);
            acc0.x += w1*b2f(v1[0]); acc0.y += w1*b2f(v1[1]); acc0.z += w1*b2f(v1[2]); acc0.w += w1*b2f(v1[3]);
            acc1.x += w1*b2f(v1[4]); acc1.y += w1*b2f(v1[5]); acc1.z += w1*b2f(v1[6]); acc1.w += w1*b2f(v1[7]);
            acc0.x += w2*b2f(v2[0]); acc0.y += w2*b2f(v2[1]); acc0.z += w2*b2f(v2[2]); acc0.w += w2*b2f(v2[3]);
            acc1.x += w2*b2f(v2[4]); acc1.y += w2*b2f(v2[5]); acc1.z += w2*b2f(v2[6]); acc1.w += w2*b2f(v2[7]);
            acc0.x += w3*b2f(v3[0]); acc0.y += w3*b2f(v3[1]); acc0.z += w3*b2f(v3[2]); acc0.w += w3*b2f(v3[3]);
            acc1.x += w3*b2f(v3[4]); acc1.y += w3*b2f(v3[5]); acc1.z += w3*b2f(v3[6]); acc1.w += w3*b2f(v3[7]);
        }
        for (; j + 4 <= cn; j += 4) {
            do_edge(j + hi);
            do_edge(j + 2 + hi);
        }
        for (; j < cn; j += 2) {
            int jj = j + hi;
            if (jj < cn) do_edge(jj);
        }
    };

    if (deg <= 64) {
        run_chunk(deg);
    } else {
        for (int c0 = 0; c0 < deg; c0 += 64) {
            int idx = beg + c0 + lane;
            if (idx < end) {
                int s = csr_src[idx];
                float4 e = f4add(asrc4[s], adstv);
                e.x = e.x > 0.f ? e.x : 0.2f * e.x;
                e.y = e.y > 0.f ? e.y : 0.2f * e.y;
                e.z = e.z > 0.f ? e.z : 0.2f * e.z;
                e.w = e.w > 0.f ? e.w : 0.2f * e.w;
                exbuf[wv][lane] = f4exp(f4sub(e, m));
                sbuf[wv][lane]  = s;
            }
            int cn = deg - c0; if (cn > 64) cn = 64;
            run_chunk(cn);
        }
    }

    // combine half-wave partials (both halves end with the full sums)
    acc0.x += __shfl_xor(acc0.x, 32); acc0.y += __shfl_xor(acc0.y, 32);
    acc0.z += __shfl_xor(acc0.z, 32); acc0.w += __shfl_xor(acc0.w, 32);
    acc1.x += __shfl_xor(acc1.x, 32); acc1.y += __shfl_xor(acc1.y, 32);
    acc1.z += __shfl_xor(acc1.z, 32); acc1.w += __shfl_xor(acc1.w, 32);

    const float4* b4 = (const float4*)bias;
    float4* op = (float4*)(out + (size_t)node * HC);
    if (hi == 0) {
        float4 bv = b4[ll * 2];
        op[ll * 2] = make_float4(acc0.x * inv + bv.x, acc0.y * inv + bv.y,
                                 acc0.z * inv + bv.z, acc0.w * inv + bv.w);
    } else {
        float4 bv = b4[ll * 2 + 1];
        op[ll * 2 + 1] = make_float4(acc1.x * inv + bv.x, acc1.y * inv + bv.y,
                                     acc1.z * inv + bv.z, acc1.w * inv + bv.w);
    }
}

// ---------------------------------------------------------------------------
extern "C" void kernel_launch(void* const* d_in, const int* in_sizes, int n_in,
                              void* d_out, int out_size, void* d_ws, size_t ws_size,
                              hipStream_t stream) {
    const float* x       = (const float*)d_in[0];
    const int*   ei      = (const int*)d_in[1];
    const float* W1      = (const float*)d_in[2];
    const float* b1      = (const float*)d_in[3];
    const float* W2      = (const float*)d_in[4];
    const float* b2      = (const float*)d_in[5];
    const float* Wg      = (const float*)d_in[6];
    const float* att_src = (const float*)d_in[7];
    const float* att_dst = (const float*)d_in[8];
    const float* bias_g  = (const float*)d_in[9];

    const int Nn = in_sizes[0] / FIN;       // 20000
    const int E  = in_sizes[1] / 2;         // 320000
    const int* e_src = ei;
    const int* e_dst = ei + E;

    char* w = (char*)d_ws;
    auto alloc = [&](size_t bytes) { char* p = w; w += (bytes + 255) & ~(size_t)255; return p; };
    unsigned short* W1t  = (unsigned short*)alloc((size_t)OUTD * FIN * 2);
    unsigned short* W2gt = (unsigned short*)alloc((size_t)HC * HIDD * 2);
    float* b2g  = (float*)alloc(HC * 4);
    unsigned short* h1  = (unsigned short*)alloc((size_t)Nn * HIDD * 2);
    unsigned short* xgb = (unsigned short*)alloc((size_t)Nn * HC * 2);
    float* asrc = (float*)alloc((size_t)Nn * NH * 4);
    float* adst = (float*)alloc((size_t)Nn * NH * 4);
    int* deg    = (int*)alloc((size_t)Nn * 4);
    int* offs   = (int*)alloc((size_t)(Nn + 1) * 4);
    int* cursor = (int*)alloc((size_t)Nn * 4);
    int* csr    = (int*)alloc((size_t)(E + Nn) * 4);

    dim3 blk(256);

    // 1) prep: W1t | W2gt+b2g | deg=1
    {
        int total = FIN * HIDD + HC * HIDD + Nn;
        prep_kernel<<<dim3((total + 255) / 256), blk, 0, stream>>>(
            W1, W1t, W2, b2, Wg, W2gt, b2g, deg, Nn);
    }

    // 2) h1 = relu(x@W1 + b1)  [bf16], BM=32 -> 625 blocks
    mfma_gemm_kernel<true, true, 32><<<dim3((Nn + 31) / 32, 1), blk, 0, stream>>>(
        x, W1t, b1, h1, Nn, HIDD, FIN, 1);
    // 3) xg = h1 @ W2g + b2g   [bf16], BM=64 -> 626 blocks
    mfma_gemm_kernel<false, true, 64><<<dim3((Nn + 63) / 64, 2), blk, 0, stream>>>(
        h1, W2gt, b2g, xgb, Nn, HC, HIDD, 0);

    // 4) attention dots + degree count (fused)
    {
        int nb_dots = (Nn * NH + 255) / 256;          // 313
        int nb_cnt  = (E + 255) / 256;                // 1250
        dots_count_kernel<<<dim3(nb_dots + nb_cnt), blk, 0, stream>>>(
            xgb, att_src, att_dst, asrc, adst, e_dst, deg, Nn, E, nb_dots);
    }

    // 5) scan
    scan_offsets_kernel<<<dim3(1), dim3(1024), 0, stream>>>(deg, offs, cursor, Nn);
    // 6) scatter
    scatter_kernel<<<dim3((E + Nn + 255) / 256), blk, 0, stream>>>(
        e_src, e_dst, cursor, csr, E, Nn);

    // 7) softmax + aggregation
    gat_aggregate3_kernel<<<dim3((Nn + 3) / 4), blk, 0, stream>>>(
        xgb, (const float4*)asrc, (const float4*)adst, offs, csr, bias_g,
        (float*)d_out, Nn);
}

// Round 5
// 126.972 us; speedup vs baseline: 2.0368x; 1.0248x over previous
//
#include <hip/hip_runtime.h>
#include <math.h>

// Problem constants (fixed by the reference)
#define NNODES 20000
#define NEDGES 320000
#define FIN    512
#define HIDD   128
#define OUTD   128
#define NH     4
#define NC     64
#define HC     256   // NH*NC

typedef short bf16x8 __attribute__((ext_vector_type(8)));
typedef float f32x4  __attribute__((ext_vector_type(4)));

__device__ __forceinline__ unsigned short f2bf(float f) {
    unsigned int u = __float_as_uint(f);
    unsigned int r = 0x7fffu + ((u >> 16) & 1u);
    return (unsigned short)((u + r) >> 16);
}
__device__ __forceinline__ float b2f(short t) {
    return __uint_as_float(((unsigned)(unsigned short)t) << 16);
}
__device__ __forceinline__ float4 f4max(float4 a, float4 b) {
    return make_float4(fmaxf(a.x,b.x), fmaxf(a.y,b.y), fmaxf(a.z,b.z), fmaxf(a.w,b.w));
}
__device__ __forceinline__ float4 f4add(float4 a, float4 b) {
    return make_float4(a.x+b.x, a.y+b.y, a.z+b.z, a.w+b.w);
}
__device__ __forceinline__ float4 f4sub(float4 a, float4 b) {
    return make_float4(a.x-b.x, a.y-b.y, a.z-b.z, a.w-b.w);
}
__device__ __forceinline__ float4 f4mul(float4 a, float4 b) {
    return make_float4(a.x*b.x, a.y*b.y, a.z*b.z, a.w*b.w);
}
__device__ __forceinline__ float4 f4exp(float4 a) {
    return make_float4(__expf(a.x), __expf(a.y), __expf(a.z), __expf(a.w));
}
__device__ __forceinline__ float4 shflx4(float4 v, int m) {
    return make_float4(__shfl_xor(v.x,m), __shfl_xor(v.y,m), __shfl_xor(v.z,m), __shfl_xor(v.w,m));
}

// ---------------------------------------------------------------------------
// Prep (fused): W1t transpose-cast | W2@Wg fuse + b2g | deg init (=1 self loop)
// ---------------------------------------------------------------------------
__global__ __launch_bounds__(256)
void prep_kernel(const float* __restrict__ W1, unsigned short* __restrict__ W1t,
                 const float* __restrict__ W2, const float* __restrict__ b2,
                 const float* __restrict__ Wg, unsigned short* __restrict__ W2gt,
                 float* __restrict__ b2g, int* __restrict__ deg, int n) {
    const int T1 = FIN * HIDD;      // 65536
    const int T2 = HC * HIDD;       // 32768
    int idx = blockIdx.x * 256 + threadIdx.x;
    if (idx < T1) {
        int nn = idx / FIN, k = idx % FIN;
        W1t[idx] = f2bf(W1[(size_t)k * HIDD + nn]);
    } else if (idx < T1 + T2) {
        int local = idx - T1;
        int nn = local >> 7;         // 0..255 output col
        int k  = local & 127;        // 0..127 input row
        float s = 0.f;
        #pragma unroll 8
        for (int t = 0; t < HIDD; ++t)
            s += W2[(size_t)k * OUTD + t] * Wg[(size_t)t * HC + nn];
        W2gt[(size_t)nn * HIDD + k] = f2bf(s);
        if (k == 0) {
            float t2 = 0.f;
            #pragma unroll 8
            for (int t = 0; t < OUTD; ++t) t2 += b2[t] * Wg[(size_t)t * HC + nn];
            b2g[nn] = t2;
        }
    } else if (idx < T1 + T2 + n) {
        deg[idx - T1 - T2] = 1;     // self loop
    }
}

// ---------------------------------------------------------------------------
// GEMM1 (+ fused degree count): h1 = relu(x @ W1t^T + b1)  [bf16 out]
//   BM=32, BN=128(=N), BK=64; 4 waves (2x2); XOR-swizzled LDS.
//   Blocks >= gemmBlocks do the edge-degree atomic count instead (overlapped:
//   count is atomic-latency-bound, gemm is MFMA/LDS-bound).
// ---------------------------------------------------------------------------
__global__ __launch_bounds__(256)
void gemm1_count_kernel(const float* __restrict__ A,            // x [M][512] fp32
                        const unsigned short* __restrict__ Bt,  // W1t [128][512]
                        const float* __restrict__ bias,         // b1
                        unsigned short* __restrict__ C,         // h1 [M][128]
                        const int* __restrict__ dst, int* __restrict__ deg,
                        int M, int E, int gemmBlocks) {
    __shared__ unsigned short As[32 * 64];    // 4 KB
    __shared__ unsigned short Bs[128 * 64];   // 16 KB

    if ((int)blockIdx.x >= gemmBlocks) {
        int i = ((int)blockIdx.x - gemmBlocks) * 256 + threadIdx.x;
        if (i < E) atomicAdd(&deg[dst[i]], 1);
        return;
    }

    const int tid  = threadIdx.x;
    const int lane = tid & 63;
    const int w    = tid >> 6;
    const int wr   = w >> 1;
    const int wc   = w & 1;
    const int m0   = blockIdx.x * 32;

    char* pA = (char*)As;
    char* pB = (char*)Bs;

    f32x4 acc[4];
    #pragma unroll
    for (int n = 0; n < 4; ++n) acc[n] = (f32x4){0.f, 0.f, 0.f, 0.f};

    for (int k0 = 0; k0 < FIN; k0 += 64) {
        // stage A (32 rows x 64 k), fp32 -> bf16
        {
            const int row = tid >> 3;                // 0..31
            const int sg  = tid & 7;                 // 8-float segment
            const bool ok = (m0 + row) < M;
            const float4* Ap = (const float4*)(A + (size_t)(m0 + row) * FIN + k0 + sg * 8);
            float4 f0 = make_float4(0,0,0,0), f1 = f0;
            if (ok) { f0 = Ap[0]; f1 = Ap[1]; }
            unsigned short u[8];
            u[0]=f2bf(f0.x); u[1]=f2bf(f0.y); u[2]=f2bf(f0.z); u[3]=f2bf(f0.w);
            u[4]=f2bf(f1.x); u[5]=f2bf(f1.y); u[6]=f2bf(f1.z); u[7]=f2bf(f1.w);
            *(bf16x8*)(pA + (((row * 128 + sg * 16)) ^ ((row & 7) << 4))) = *(bf16x8*)&u[0];
        }
        // stage B (128 cols x 64 k)
        #pragma unroll
        for (int i = 0; i < 4; ++i) {
            int s   = tid + i * 256;
            int col = s >> 3;
            int sg  = s & 7;
            bf16x8 v = *(const bf16x8*)(Bt + (size_t)col * FIN + k0 + sg * 8);
            *(bf16x8*)(pB + (((col * 128 + sg * 16)) ^ ((col & 7) << 4))) = v;
        }
        __syncthreads();

        #pragma unroll
        for (int ks = 0; ks < 2; ++ks) {
            const int kb = ks * 64 + ((lane >> 4) << 4);
            int row = wr * 16 + (lane & 15);
            bf16x8 a = *(const bf16x8*)(pA + ((row * 128 + kb) ^ ((row & 7) << 4)));
            bf16x8 b[4];
            #pragma unroll
            for (int n = 0; n < 4; ++n) {
                int col = wc * 64 + n * 16 + (lane & 15);
                b[n] = *(const bf16x8*)(pB + ((col * 128 + kb) ^ ((col & 7) << 4)));
            }
            #pragma unroll
            for (int n = 0; n < 4; ++n)
                acc[n] = __builtin_amdgcn_mfma_f32_16x16x32_bf16(a, b[n], acc[n], 0, 0, 0);
        }
        __syncthreads();
    }

    #pragma unroll
    for (int n = 0; n < 4; ++n) {
        const int col = wc * 64 + n * 16 + (lane & 15);
        const float bv = bias[col];
        #pragma unroll
        for (int r = 0; r < 4; ++r) {
            const int row = m0 + wr * 16 + ((lane >> 4) << 2) + r;
            if (row >= M) continue;
            float v = fmaxf(acc[n][r] + bv, 0.f);
            C[(size_t)row * HIDD + col] = f2bf(v);
        }
    }
}

// ---------------------------------------------------------------------------
// GEMM2 (+ fused attention dots): xgb = h1 @ W2gt^T + b2g  [bf16 out]
//   BM=64, BN=128, K=128; 4 waves (2x2).
//   Each wave's 32x64 output tile is exactly one head's channels for 32 rows
//   -> per-thread FMA vs att vectors + 16-lane shfl reduce gives a_src/a_dst.
// ---------------------------------------------------------------------------
__global__ __launch_bounds__(256)
void gemm2_dots_kernel(const unsigned short* __restrict__ Ab,   // h1 [M][128] bf16
                       const unsigned short* __restrict__ Bt,   // W2gt [256][128] bf16
                       const float* __restrict__ b2g,           // [256]
                       const float* __restrict__ att_src,       // [4][64]
                       const float* __restrict__ att_dst,       // [4][64]
                       unsigned short* __restrict__ xgb,        // [M][256] bf16
                       float* __restrict__ a_src, float* __restrict__ a_dst,
                       int M) {
    __shared__ unsigned short As[64 * 64];    // 8 KB
    __shared__ unsigned short Bs[128 * 64];   // 16 KB

    const int tid  = threadIdx.x;
    const int lane = tid & 63;
    const int w    = tid >> 6;
    const int wr   = w >> 1;
    const int wc   = w & 1;
    const int m0   = blockIdx.x * 64;
    const int n0   = blockIdx.y * 128;

    char* pA = (char*)As;
    char* pB = (char*)Bs;

    f32x4 acc[2][4];
    #pragma unroll
    for (int m = 0; m < 2; ++m)
        #pragma unroll
        for (int n = 0; n < 4; ++n) acc[m][n] = (f32x4){0.f, 0.f, 0.f, 0.f};

    for (int k0 = 0; k0 < HIDD; k0 += 64) {
        #pragma unroll
        for (int i = 0; i < 2; ++i) {
            int s   = tid + i * 256;
            int row = s >> 3;
            int sg  = s & 7;
            bf16x8 v = {};
            if ((m0 + row) < M)
                v = *(const bf16x8*)(Ab + (size_t)(m0 + row) * HIDD + k0 + sg * 8);
            *(bf16x8*)(pA + (((row * 128 + sg * 16)) ^ ((row & 7) << 4))) = v;
        }
        #pragma unroll
        for (int i = 0; i < 4; ++i) {
            int s   = tid + i * 256;
            int col = s >> 3;
            int sg  = s & 7;
            bf16x8 v = *(const bf16x8*)(Bt + (size_t)(n0 + col) * HIDD + k0 + sg * 8);
            *(bf16x8*)(pB + (((col * 128 + sg * 16)) ^ ((col & 7) << 4))) = v;
        }
        __syncthreads();

        #pragma unroll
        for (int ks = 0; ks < 2; ++ks) {
            const int kb = ks * 64 + ((lane >> 4) << 4);
            bf16x8 a[2], b[4];
            #pragma unroll
            for (int m = 0; m < 2; ++m) {
                int row = wr * 32 + m * 16 + (lane & 15);
                a[m] = *(const bf16x8*)(pA + ((row * 128 + kb) ^ ((row & 7) << 4)));
            }
            #pragma unroll
            for (int n = 0; n < 4; ++n) {
                int col = wc * 64 + n * 16 + (lane & 15);
                b[n] = *(const bf16x8*)(pB + ((col * 128 + kb) ^ ((col & 7) << 4)));
            }
            #pragma unroll
            for (int m = 0; m < 2; ++m)
                #pragma unroll
                for (int n = 0; n < 4; ++n)
                    acc[m][n] = __builtin_amdgcn_mfma_f32_16x16x32_bf16(
                        a[m], b[n], acc[m][n], 0, 0, 0);
        }
        __syncthreads();
    }

    // ---- epilogue: store xgb + per-head attention dots ----
    const int head = blockIdx.y * 2 + wc;            // 0..3
    const int cIn  = lane & 15;
    float ds_p[2][4], dd_p[2][4];
    #pragma unroll
    for (int m = 0; m < 2; ++m)
        #pragma unroll
        for (int r = 0; r < 4; ++r) { ds_p[m][r] = 0.f; dd_p[m][r] = 0.f; }

    #pragma unroll
    for (int n = 0; n < 4; ++n) {
        const int ch  = n * 16 + cIn;                // channel within head, 0..63
        const int col = n0 + wc * 64 + n * 16 + cIn;
        const float bv   = b2g[col];
        const float as_c = att_src[head * NC + ch];
        const float ad_c = att_dst[head * NC + ch];
        #pragma unroll
        for (int m = 0; m < 2; ++m) {
            #pragma unroll
            for (int r = 0; r < 4; ++r) {
                const int row = m0 + wr * 32 + m * 16 + ((lane >> 4) << 2) + r;
                float v = acc[m][n][r] + bv;
                if (row < M) xgb[(size_t)row * HC + col] = f2bf(v);
                ds_p[m][r] += v * as_c;
                dd_p[m][r] += v * ad_c;
            }
        }
    }
    #pragma unroll
    for (int m = 0; m < 2; ++m) {
        #pragma unroll
        for (int r = 0; r < 4; ++r) {
            float s = ds_p[m][r], d = dd_p[m][r];
            s += __shfl_xor(s, 1); s += __shfl_xor(s, 2);
            s += __shfl_xor(s, 4); s += __shfl_xor(s, 8);
            d += __shfl_xor(d, 1); d += __shfl_xor(d, 2);
            d += __shfl_xor(d, 4); d += __shfl_xor(d, 8);
            if (cIn == 0) {
                const int row = m0 + wr * 32 + m * 16 + ((lane >> 4) << 2) + r;
                if (row < M) {
                    a_src[row * NH + head] = s;
                    a_dst[row * NH + head] = d;
                }
            }
        }
    }
}

// ---------------------------------------------------------------------------
// Single-block scan, 20 elems/thread in registers, 2 barriers. n <= 20480.
// ---------------------------------------------------------------------------
__global__ __launch_bounds__(1024)
void scan_offsets_kernel(const int* __restrict__ deg, int* __restrict__ offs,
                         int* __restrict__ cursor, int n) {
    __shared__ int wsum[16], wbase[16];
    const int tid = threadIdx.x, lane = tid & 63, w = tid >> 6;
    const int i0 = tid * 20;
    int loc[20];
    int s = 0;
    #pragma unroll
    for (int k = 0; k < 20; ++k) {
        int i = i0 + k;
        int v = (i < n) ? deg[i] : 0;
        loc[k] = s;
        s += v;
    }
    int incl = s;
    #pragma unroll
    for (int d = 1; d < 64; d <<= 1) {
        int t = __shfl_up(incl, d);
        if (lane >= d) incl += t;
    }
    if (lane == 63) wsum[w] = incl;
    __syncthreads();
    if (w == 0) {
        int v = (lane < 16) ? wsum[lane] : 0;
        int sc = v;
        #pragma unroll
        for (int d = 1; d < 16; d <<= 1) {
            int t = __shfl_up(sc, d);
            if (lane >= d) sc += t;
        }
        if (lane < 16) wbase[lane] = sc - v;
    }
    __syncthreads();
    const int excl = wbase[w] + incl - s;
    #pragma unroll
    for (int k = 0; k < 20; ++k) {
        int i = i0 + k;
        if (i < n) { int o = excl + loc[k]; offs[i] = o; cursor[i] = o; }
    }
    if (tid == 1023) offs[n] = excl + s;
}

// ---------------------------------------------------------------------------
// Scatter edges (and self-loops) into CSR slots
// ---------------------------------------------------------------------------
__global__ void scatter_kernel(const int* __restrict__ src, const int* __restrict__ dst,
                               int* __restrict__ cursor, int* __restrict__ csr_src,
                               int e, int n) {
    int i = blockIdx.x * 256 + threadIdx.x;
    if (i < e) {
        int s = src[i], d = dst[i];
        csr_src[atomicAdd(&cursor[d], 1)] = s;
    } else if (i < e + n) {
        int node = i - e;
        csr_src[atomicAdd(&cursor[node], 1)] = node;
    }
}

// ---------------------------------------------------------------------------
// Aggregation v4: one wave per node.
// Pass A: lane-parallel softmax; logits from asrc gather (L2-resident) +
//         wave-uniform adst; exp/src cached in LDS.
// Pass B: half-wave channel split; 16-edge unroll (8 gathers in flight/lane).
// ---------------------------------------------------------------------------
__global__ __launch_bounds__(256)
void gat_aggregate4_kernel(const unsigned short* __restrict__ xgb,
                           const float4* __restrict__ asrc4,
                           const float4* __restrict__ adst4,
                           const int* __restrict__ offs, const int* __restrict__ csr_src,
                           const float* __restrict__ bias, float* __restrict__ out, int n) {
    __shared__ float4 exbuf[4][64];
    __shared__ int    sbuf[4][64];
    const int wv   = threadIdx.x >> 6;
    const int lane = threadIdx.x & 63;
    const int node = blockIdx.x * 4 + wv;
    if (node >= n) return;
    const int beg = offs[node], end = offs[node + 1];
    const int deg = end - beg;
    const float4 adstv = adst4[node];

    // ---- pass A ----
    float4 m   = make_float4(-INFINITY, -INFINITY, -INFINITY, -INFINITY);
    float4 den = make_float4(0.f, 0.f, 0.f, 0.f);
    for (int c0 = 0; c0 < deg; c0 += 64) {
        int idx = beg + c0 + lane;
        bool ok = idx < end;
        int s = ok ? csr_src[idx] : 0;
        float4 e = make_float4(-INFINITY, -INFINITY, -INFINITY, -INFINITY);
        if (ok) {
            float4 a = asrc4[s];
            e = f4add(a, adstv);
            e.x = e.x > 0.f ? e.x : 0.2f * e.x;
            e.y = e.y > 0.f ? e.y : 0.2f * e.y;
            e.z = e.z > 0.f ? e.z : 0.2f * e.z;
            e.w = e.w > 0.f ? e.w : 0.2f * e.w;
        }
        float4 cm = e;
        #pragma unroll
        for (int dd = 32; dd >= 1; dd >>= 1) cm = f4max(cm, shflx4(cm, dd));
        float4 nm = f4max(m, cm);
        float4 ex = f4exp(f4sub(e, nm));      // masked lanes: exp(-inf)=0
        exbuf[wv][lane] = ex;
        sbuf[wv][lane]  = s;
        float4 cs = ex;
        #pragma unroll
        for (int dd = 32; dd >= 1; dd >>= 1) cs = f4add(cs, shflx4(cs, dd));
        den = f4add(f4mul(den, f4exp(f4sub(m, nm))), cs);
        m = nm;
    }

    const int hi = lane >> 5;
    const int ll = lane & 31;       // owns channels 8*ll .. 8*ll+7
    const int h  = ll >> 3;
    const float denh = (h == 0) ? den.x : (h == 1) ? den.y : (h == 2) ? den.z : den.w;
    const float inv = 1.f / (denh + 1e-16f);

    float4 acc0 = make_float4(0.f, 0.f, 0.f, 0.f);
    float4 acc1 = make_float4(0.f, 0.f, 0.f, 0.f);
    const float* exf = (const float*)&exbuf[wv][0];

    auto do_edge = [&](int jj) {
        int s = sbuf[wv][jj];
        float wgt = exf[jj * 4 + h];
        bf16x8 v = *(const bf16x8*)(xgb + (size_t)s * HC + ll * 8);
        acc0.x += wgt * b2f(v[0]); acc0.y += wgt * b2f(v[1]);
        acc0.z += wgt * b2f(v[2]); acc0.w += wgt * b2f(v[3]);
        acc1.x += wgt * b2f(v[4]); acc1.y += wgt * b2f(v[5]);
        acc1.z += wgt * b2f(v[6]); acc1.w += wgt * b2f(v[7]);
    };

    auto run_chunk = [&](int cn) {
        int j = 0;
        for (; j + 16 <= cn; j += 16) {
            int ss[8]; float ww[8]; bf16x8 vv[8];
            #pragma unroll
            for (int t = 0; t < 8; ++t) {
                int jj = j + 2 * t + hi;
                ss[t] = sbuf[wv][jj];
                ww[t] = exf[jj * 4 + h];
            }
            #pragma unroll
            for (int t = 0; t < 8; ++t)
                vv[t] = *(const bf16x8*)(xgb + (size_t)ss[t] * HC + ll * 8);
            #pragma unroll
            for (int t = 0; t < 8; ++t) {
                acc0.x += ww[t]*b2f(vv[t][0]); acc0.y += ww[t]*b2f(vv[t][1]);
                acc0.z += ww[t]*b2f(vv[t][2]); acc0.w += ww[t]*b2f(vv[t][3]);
                acc1.x += ww[t]*b2f(vv[t][4]); acc1.y += ww[t]*b2f(vv[t][5]);
                acc1.z += ww[t]*b2f(vv[t][6]); acc1.w += ww[t]*b2f(vv[t][7]);
            }
        }
        for (; j + 8 <= cn; j += 8) {
            do_edge(j + hi);     do_edge(j + 2 + hi);
            do_edge(j + 4 + hi); do_edge(j + 6 + hi);
        }
        for (; j + 4 <= cn; j += 4) {
            do_edge(j + hi);
            do_edge(j + 2 + hi);
        }
        for (; j < cn; j += 2) {
            int jj = j + hi;
            if (jj < cn) do_edge(jj);
        }
    };

    if (deg <= 64) {
        run_chunk(deg);
    } else {
        for (int c0 = 0; c0 < deg; c0 += 64) {
            int idx = beg + c0 + lane;
            if (idx < end) {
                int s = csr_src[idx];
                float4 e = f4add(asrc4[s], adstv);
                e.x = e.x > 0.f ? e.x : 0.2f * e.x;
                e.y = e.y > 0.f ? e.y : 0.2f * e.y;
                e.z = e.z > 0.f ? e.z : 0.2f * e.z;
                e.w = e.w > 0.f ? e.w : 0.2f * e.w;
                exbuf[wv][lane] = f4exp(f4sub(e, m));
                sbuf[wv][lane]  = s;
            }
            int cn = deg - c0; if (cn > 64) cn = 64;
            run_chunk(cn);
        }
    }

    // combine half-wave partials
    acc0.x += __shfl_xor(acc0.x, 32); acc0.y += __shfl_xor(acc0.y, 32);
    acc0.z += __shfl_xor(acc0.z, 32); acc0.w += __shfl_xor(acc0.w, 32);
    acc1.x += __shfl_xor(acc1.x, 32); acc1.y += __shfl_xor(acc1.y, 32);
    acc1.z += __shfl_xor(acc1.z, 32); acc1.w += __shfl_xor(acc1.w, 32);

    const float4* b4 = (const float4*)bias;
    float4* op = (float4*)(out + (size_t)node * HC);
    if (hi == 0) {
        float4 bv = b4[ll * 2];
        op[ll * 2] = make_float4(acc0.x * inv + bv.x, acc0.y * inv + bv.y,
                                 acc0.z * inv + bv.z, acc0.w * inv + bv.w);
    } else {
        float4 bv = b4[ll * 2 + 1];
        op[ll * 2 + 1] = make_float4(acc1.x * inv + bv.x, acc1.y * inv + bv.y,
                                     acc1.z * inv + bv.z, acc1.w * inv + bv.w);
    }
}

// ---------------------------------------------------------------------------
extern "C" void kernel_launch(void* const* d_in, const int* in_sizes, int n_in,
                              void* d_out, int out_size, void* d_ws, size_t ws_size,
                              hipStream_t stream) {
    const float* x       = (const float*)d_in[0];
    const int*   ei      = (const int*)d_in[1];
    const float* W1      = (const float*)d_in[2];
    const float* b1      = (const float*)d_in[3];
    const float* W2      = (const float*)d_in[4];
    const float* b2      = (const float*)d_in[5];
    const float* Wg      = (const float*)d_in[6];
    const float* att_src = (const float*)d_in[7];
    const float* att_dst = (const float*)d_in[8];
    const float* bias_g  = (const float*)d_in[9];

    const int Nn = in_sizes[0] / FIN;       // 20000
    const int E  = in_sizes[1] / 2;         // 320000
    const int* e_src = ei;
    const int* e_dst = ei + E;

    char* w = (char*)d_ws;
    auto alloc = [&](size_t bytes) { char* p = w; w += (bytes + 255) & ~(size_t)255; return p; };
    unsigned short* W1t  = (unsigned short*)alloc((size_t)OUTD * FIN * 2);
    unsigned short* W2gt = (unsigned short*)alloc((size_t)HC * HIDD * 2);
    float* b2g  = (float*)alloc(HC * 4);
    unsigned short* h1  = (unsigned short*)alloc((size_t)Nn * HIDD * 2);
    unsigned short* xgb = (unsigned short*)alloc((size_t)Nn * HC * 2);
    float* asrc = (float*)alloc((size_t)Nn * NH * 4);
    float* adst = (float*)alloc((size_t)Nn * NH * 4);
    int* deg    = (int*)alloc((size_t)Nn * 4);
    int* offs   = (int*)alloc((size_t)(Nn + 1) * 4);
    int* cursor = (int*)alloc((size_t)Nn * 4);
    int* csr    = (int*)alloc((size_t)(E + Nn) * 4);

    dim3 blk(256);

    // 1) prep: W1t | W2gt+b2g | deg=1
    {
        int total = FIN * HIDD + HC * HIDD + Nn;
        prep_kernel<<<dim3((total + 255) / 256), blk, 0, stream>>>(
            W1, W1t, W2, b2, Wg, W2gt, b2g, deg, Nn);
    }

    // 2) h1 = relu(x@W1 + b1)  [bf16]  + fused degree count
    {
        int gb = (Nn + 31) / 32;                 // 625 gemm blocks
        int cb = (E + 255) / 256;                // 1250 count blocks
        gemm1_count_kernel<<<dim3(gb + cb), blk, 0, stream>>>(
            x, W1t, b1, h1, e_dst, deg, Nn, E, gb);
    }

    // 3) xg = h1 @ W2g + b2g [bf16] + fused attention dots
    gemm2_dots_kernel<<<dim3((Nn + 63) / 64, 2), blk, 0, stream>>>(
        h1, W2gt, b2g, att_src, att_dst, xgb, asrc, adst, Nn);

    // 4) scan
    scan_offsets_kernel<<<dim3(1), dim3(1024), 0, stream>>>(deg, offs, cursor, Nn);
    // 5) scatter
    scatter_kernel<<<dim3((E + Nn + 255) / 256), blk, 0, stream>>>(
        e_src, e_dst, cursor, csr, E, Nn);

    // 6) softmax + aggregation
    gat_aggregate4_kernel<<<dim3((Nn + 3) / 4), blk, 0, stream>>>(
        xgb, (const float4*)asrc, (const float4*)adst, offs, csr, bias_g,
        (float*)d_out, Nn);
}